// Round 5
// baseline (5074.720 us; speedup 1.0000x reference)
//
#include <hip/hip_runtime.h>
#include <stdint.h>

#define BB 8
#define NN 16384
#define SS 1024

// ---------------- FPS: one block per batch, exact np fp32 semantics ----------------
__global__ __launch_bounds__(1024) void fps_kernel(const float* __restrict__ xyz, int* __restrict__ fps_idx){
#pragma clang fp contract(off)
    int b = blockIdx.x;
    int t = threadIdx.x;
    const float* xb = xyz + (size_t)b*3*NN;
    float px[16], py[16], pz[16], dd[16];
#pragma unroll
    for (int j=0;j<16;++j){
        int n = t + j*1024;
        px[j] = xb[n];
        py[j] = xb[NN+n];
        pz[j] = xb[2*NN+n];
        dd[j] = 1e10f;
    }
    __shared__ float rv[16];
    __shared__ int   rn[16];
    __shared__ int   s_far;
    int far = 0;
    int* outp = fps_idx + b*SS;
    for (int it=0; it<SS; ++it){
        if (t==0) outp[it] = far;
        float cx = xb[far];
        float cy = xb[NN+far];
        float cz = xb[2*NN+far];
        float bestv = -1.0f; int bestn = 0x7fffffff;
#pragma unroll
        for (int j=0;j<16;++j){
            float dx = px[j]-cx, dy = py[j]-cy, dz = pz[j]-cz;
            float d = dx*dx + dy*dy;
            d = d + dz*dz;
            float dm = dd[j] < d ? dd[j] : d;   // np.minimum
            dd[j] = dm;
            int n = t + j*1024;
            if (dm > bestv){ bestv = dm; bestn = n; }  // strict > keeps lowest n
        }
        for (int off=32; off>0; off>>=1){
            float ov = __shfl_down(bestv, off);
            int   on = __shfl_down(bestn, off);
            if (ov > bestv || (ov == bestv && on < bestn)){ bestv = ov; bestn = on; }
        }
        int wid = t >> 6;
        if ((t & 63) == 0){ rv[wid] = bestv; rn[wid] = bestn; }
        __syncthreads();
        if (t < 64){
            float v2 = (t < 16) ? rv[t] : -1.0f;
            int   n2 = (t < 16) ? rn[t] : 0x7fffffff;
            for (int off=8; off>0; off>>=1){
                float ov = __shfl_down(v2, off);
                int   on = __shfl_down(n2, off);
                if (ov > v2 || (ov == v2 && on < n2)){ v2 = ov; n2 = on; }
            }
            if (t==0) s_far = n2;
        }
        __syncthreads();
        far = s_far;
    }
}

// ---------------- gather query coords + write new_xyz output (fp32) ----------------
__global__ void gather_q_kernel(const float* __restrict__ xyz, const int* __restrict__ fps_idx,
                                float* __restrict__ q, float* __restrict__ out_xyz){
    int i = blockIdx.x*blockDim.x + threadIdx.x;
    if (i >= BB*SS) return;
    int b = i >> 10, s = i & 1023;
    int idx = fps_idx[i];
    for (int c=0;c<3;++c){
        float v = xyz[((size_t)b*3+c)*NN + idx];
        q[i*3+c] = v;
        out_xyz[((size_t)b*3+c)*SS + s] = v;
    }
}

// ---------------- build ptsT[b][n][64]: c0..2 = xyz, c3..63 = points ----------------
__global__ __launch_bounds__(256) void build_ptsT_kernel(const float* __restrict__ xyz, const float* __restrict__ pts,
                                                         float* __restrict__ ptsT){
    __shared__ float tile[64][65];
    int b = blockIdx.y;
    int n0 = blockIdx.x * 64;
    int t = threadIdx.x;
    int ln = t & 63, cr = t >> 6;
    for (int c = cr; c < 64; c += 4){
        float v;
        if (c < 3) v = xyz[((size_t)b*3 + c)*NN + n0 + ln];
        else       v = pts[((size_t)b*61 + (c-3))*NN + n0 + ln];
        tile[ln][c] = v;
    }
    __syncthreads();
    int lc = t & 63, nr = t >> 6;
    for (int n = nr; n < 64; n += 4){
        ptsT[((size_t)b*NN + n0 + n)*64 + lc] = tile[n][lc];
    }
}

// ---------------- ball query: one wave per (b,s), 3 radii fused ----------------
__global__ __launch_bounds__(256) void ballquery_kernel(const float* __restrict__ xyz, const float* __restrict__ q,
        int* __restrict__ idx0, int* __restrict__ idx1, int* __restrict__ idx2,
        float r2a, float r2b, float r2c){
#pragma clang fp contract(off)
    __shared__ int lds[4][112];
    int t = threadIdx.x;
    int w = t >> 6, lane = t & 63;
    int qi = blockIdx.x*4 + w;           // < 8192
    int b = qi >> 10;
    const float* xb = xyz + (size_t)b*3*NN;
    float qx = q[qi*3], qy = q[qi*3+1], qz = q[qi*3+2];
    float qn = qx*qx + qy*qy; qn = qn + qz*qz;
    int* l0 = lds[w];
    int* l1 = l0 + 16;
    int* l2 = l0 + 48;
    l0[lane] = 0;
    if (lane < 48) l0[64+lane] = 0;
    int c0=0, c1=0, c2=0;
    uint64_t below = (1ull << lane) - 1ull;
    for (int ch=0; ch<256; ++ch){
        int n = ch*64 + lane;
        float x = xb[n], y = xb[NN+n], z = xb[2*NN+n];
        float dn = x*x + y*y; dn = dn + z*z;
        float dot = qx*x + qy*y; dot = dot + qz*z;
        float d = -2.0f*dot + qn;
        d = d + dn;
        bool o0 = d <= r2a, o1 = d <= r2b, o2 = d <= r2c;
        uint64_t m0 = __ballot(o0), m1 = __ballot(o1), m2 = __ballot(o2);
        if (c0 < 16){
            int p = c0 + (int)__popcll(m0 & below);
            if (o0 && p < 16) l0[p] = n;
            c0 += (int)__popcll(m0); if (c0 > 16) c0 = 16;
        }
        if (c1 < 32){
            int p = c1 + (int)__popcll(m1 & below);
            if (o1 && p < 32) l1[p] = n;
            c1 += (int)__popcll(m1); if (c1 > 32) c1 = 32;
        }
        if (c2 < 64){
            int p = c2 + (int)__popcll(m2 & below);
            if (o2 && p < 64) l2[p] = n;
            c2 += (int)__popcll(m2); if (c2 > 64) c2 = 64;
        }
        if (c0>=16 && c1>=32 && c2>=64) break;
    }
    __syncthreads();
    int f0 = l0[0], f1 = l1[0], f2 = l2[0];
    if (lane >= c0 && lane < 16) l0[lane] = f0;
    if (lane >= c1 && lane < 32) l1[lane] = f1;
    if (lane >= c2)              l2[lane] = f2;
    __syncthreads();
    if (lane < 16) idx0[(size_t)qi*16 + lane] = l0[lane];
    if (lane < 32) idx1[(size_t)qi*32 + lane] = l1[lane];
    idx2[(size_t)qi*64 + lane] = l2[lane];
}

// ---------------- MAC helper ----------------
template<int UU>
__device__ __forceinline__ void fma_tile(float (&acc)[4][UU][4], float4 a4, const float* bsrow, int jbase){
#pragma unroll
    for (int uu=0; uu<UU; ++uu){
        float4 b4 = *(const float4*)(bsrow + jbase + 64*uu);
        acc[0][uu][0]+=a4.x*b4.x; acc[0][uu][1]+=a4.x*b4.y; acc[0][uu][2]+=a4.x*b4.z; acc[0][uu][3]+=a4.x*b4.w;
        acc[1][uu][0]+=a4.y*b4.x; acc[1][uu][1]+=a4.y*b4.y; acc[1][uu][2]+=a4.y*b4.z; acc[1][uu][3]+=a4.y*b4.w;
        acc[2][uu][0]+=a4.z*b4.x; acc[2][uu][1]+=a4.z*b4.y; acc[2][uu][2]+=a4.z*b4.z; acc[2][uu][3]+=a4.z*b4.w;
        acc[3][uu][0]+=a4.w*b4.x; acc[3][uu][1]+=a4.w*b4.y; acc[3][uu][2]+=a4.w*b4.z; acc[3][uu][3]+=a4.w*b4.w;
    }
}

// ---------------- stats / extrema epilogue helper ----------------
template<int UU, int K, bool EXT>
__device__ __forceinline__ void stats_write(float (&z)[4][UU][4], int t, int m0, int blk,
    float* scr, float* __restrict__ pS, float* __restrict__ pQ,
    float* __restrict__ gmax, float* __restrict__ gmin)
{
    constexpr int O = UU*64;
    int j = t & 15;
    float s1[UU][4], s2[UU][4], mx[UU][4], mn[UU][4];
#pragma unroll
    for (int uu=0; uu<UU; ++uu)
#pragma unroll
    for (int e=0; e<4; ++e){
        float v0=z[0][uu][e], v1=z[1][uu][e], v2=z[2][uu][e], v3=z[3][uu][e];
        s1[uu][e]=(v0+v1)+(v2+v3);
        s2[uu][e]=(v0*v0+v1*v1)+(v2*v2+v3*v3);
        if (EXT){
            mx[uu][e]=fmaxf(fmaxf(v0,v1),fmaxf(v2,v3));
            mn[uu][e]=fminf(fminf(v0,v1),fminf(v2,v3));
        }
    }
#pragma unroll
    for (int uu=0; uu<UU; ++uu)
#pragma unroll
    for (int e=0; e<4; ++e){
        s1[uu][e] += __shfl_xor(s1[uu][e],16); s1[uu][e] += __shfl_xor(s1[uu][e],32);
        s2[uu][e] += __shfl_xor(s2[uu][e],16); s2[uu][e] += __shfl_xor(s2[uu][e],32);
        if (EXT){
            mx[uu][e] = fmaxf(mx[uu][e], __shfl_xor(mx[uu][e],16)); mx[uu][e] = fmaxf(mx[uu][e], __shfl_xor(mx[uu][e],32));
            mn[uu][e] = fminf(mn[uu][e], __shfl_xor(mn[uu][e],16)); mn[uu][e] = fminf(mn[uu][e], __shfl_xor(mn[uu][e],32));
        }
    }
    int wv = t >> 6;
    if ((t & 63) < 16){
#pragma unroll
        for (int uu=0; uu<UU; ++uu)
#pragma unroll
        for (int e=0; e<4; ++e){
            int c = j*4 + 64*uu + e;
            scr[0*4*O + wv*O + c] = s1[uu][e];
            scr[1*4*O + wv*O + c] = s2[uu][e];
            if (EXT){
                scr[2*4*O + wv*O + c] = mx[uu][e];
                scr[3*4*O + wv*O + c] = mn[uu][e];
            }
        }
    }
    __syncthreads();
    for (int c=t; c<O; c+=256){
        float S = ((scr[c] + scr[O+c]) + (scr[2*O+c] + scr[3*O+c]));
        float Q = ((scr[4*O+c] + scr[5*O+c]) + (scr[6*O+c] + scr[7*O+c]));
        pS[(size_t)blk*O + c] = S;
        pQ[(size_t)blk*O + c] = Q;
        if (EXT){
            constexpr int G  = 64/K;
            constexpr int WG = K/16;
#pragma unroll
            for (int g=0; g<G; ++g){
                float M1 = scr[2*4*O + (g*WG)*O + c];
                float M2 = scr[3*4*O + (g*WG)*O + c];
#pragma unroll
                for (int ww=1; ww<WG; ++ww){
                    M1 = fmaxf(M1, scr[2*4*O + (g*WG+ww)*O + c]);
                    M2 = fminf(M2, scr[3*4*O + (g*WG+ww)*O + c]);
                }
                int bs = m0/K + g;
                gmax[(size_t)bs*O + c] = M1;
                gmin[(size_t)bs*O + c] = M2;
            }
        }
    }
}

// ---------------- fused MLP phases: block = 64 rows x full width, no z materialization ----------------
// Per-branch widths (O1,O2,O3): branch0 (64,64,128), branch1/2 (128,128,256).  [R4 bug: O1 was hardcoded 64]
// PHASE 1: gather -> GEMM1 -> stats1 partials
// PHASE 2: gather -> GEMM1 -> act1 -> GEMM2 -> stats2 partials
// PHASE 3: ... -> act2 -> GEMM3 -> stats3 partials + per-(b,s) max/min of z3
template<int PHASE, int K, int O1, int O2, int O3>
__global__ __launch_bounds__(256) void fused_mlp(
    const float* __restrict__ ptsT, const float* __restrict__ q, const int* __restrict__ gidx,
    const float* __restrict__ W1, const float* __restrict__ b1,
    const float* __restrict__ W2, const float* __restrict__ b2,
    const float* __restrict__ W3, const float* __restrict__ b3,
    const float* __restrict__ sc1, const float* __restrict__ sh1,
    const float* __restrict__ sc2, const float* __restrict__ sh2,
    float* __restrict__ pS, float* __restrict__ pQ,
    float* __restrict__ gmax, float* __restrict__ gmin)
{
    __shared__ float As[8192];   // 32 KB: [k][row], k up to 128
    __shared__ float Bs[4096];   // 16 KB: weight k-slabs [k][o] / stats scratch
    int t = threadIdx.x;
    int m0 = blockIdx.x * 64;
    int j = t & 15, i = t >> 4;

    // ---- gather A0 (64 rows x 64 ch) ----
    {
        int r = t >> 2, q4 = t & 3;
        int m = m0 + r;
        int idx = gidx[m];
        int bs = m / K;
        int b = bs >> 10;
        const float* base = ptsT + ((size_t)b*NN + idx)*64;
        float qx=0.f, qy=0.f, qz=0.f;
        if (q4 == 0){ qx = q[bs*3]; qy = q[bs*3+1]; qz = q[bs*3+2]; }
#pragma unroll
        for (int ii=0; ii<4; ++ii){
            int c0 = q4*16 + ii*4;
            float4 v = *(const float4*)(base + c0);
            if (q4==0 && ii==0){ v.x -= qx; v.y -= qy; v.z -= qz; }
            As[(c0+0)*64 + r] = v.x; As[(c0+1)*64 + r] = v.y;
            As[(c0+2)*64 + r] = v.z; As[(c0+3)*64 + r] = v.w;
        }
    }

    // ---- GEMM1 (C=64, O=O1, W1 stride 64), 32-k slabs ----
    constexpr int UU1 = O1/64;
    float acc1[4][UU1][4] = {};
    for (int k0=0; k0<64; k0+=32){
        __syncthreads();   // k0=0: fence gather As-writes; else: prior Bs reads done
#pragma unroll
        for (int it=0; it<O1/32; ++it){
            int slot = t + it*256;
            int o = slot >> 3, qq = slot & 7;
            float4 wv = *(const float4*)(W1 + o*64 + k0 + qq*4);
            Bs[(qq*4+0)*O1 + o] = wv.x; Bs[(qq*4+1)*O1 + o] = wv.y;
            Bs[(qq*4+2)*O1 + o] = wv.z; Bs[(qq*4+3)*O1 + o] = wv.w;
        }
        __syncthreads();
#pragma unroll 4
        for (int kk=0; kk<32; ++kk){
            float4 a4 = *(const float4*)&As[(k0+kk)*64 + i*4];
            fma_tile<UU1>(acc1, a4, &Bs[kk*O1], j*4);
        }
    }
    __syncthreads();   // GEMM1 As/Bs reads done

    if constexpr (PHASE == 1){
#pragma unroll
        for (int uu=0; uu<UU1; ++uu)
#pragma unroll
        for (int e=0; e<4; ++e){
            float bb = b1[j*4 + 64*uu + e];
#pragma unroll
            for (int rr=0; rr<4; ++rr) acc1[rr][uu][e] += bb;
        }
        stats_write<UU1,K,false>(acc1, t, m0, blockIdx.x, Bs, pS, pQ, gmax, gmin);
        return;
    }

    // ---- act1 -> As ([o1=k][row], k<O1) ----
#pragma unroll
    for (int uu=0; uu<UU1; ++uu)
#pragma unroll
    for (int e=0; e<4; ++e){
        int c = j*4 + 64*uu + e;
        float bb = b1[c], scv = sc1[c], shv = sh1[c];
#pragma unroll
        for (int rr=0; rr<4; ++rr)
            As[c*64 + i*4+rr] = fmaxf(0.f, (acc1[rr][uu][e]+bb)*scv + shv);
    }

    // ---- GEMM2 (C=O1, O=O2, W2 stride O1), 32-k slabs ----
    constexpr int UU2 = O2/64;
    float acc2[4][UU2][4] = {};
    for (int k0=0; k0<O1; k0+=32){
        __syncthreads();   // k0=0: fence act1 As-writes; else: prior Bs reads done
#pragma unroll
        for (int it=0; it<O2/32; ++it){
            int slot = t + it*256;
            int o = slot >> 3, qq = slot & 7;
            float4 wv = *(const float4*)(W2 + o*O1 + k0 + qq*4);
            Bs[(qq*4+0)*O2 + o] = wv.x; Bs[(qq*4+1)*O2 + o] = wv.y;
            Bs[(qq*4+2)*O2 + o] = wv.z; Bs[(qq*4+3)*O2 + o] = wv.w;
        }
        __syncthreads();
#pragma unroll 4
        for (int kk=0; kk<32; ++kk){
            float4 a4 = *(const float4*)&As[(k0+kk)*64 + i*4];
            fma_tile<UU2>(acc2, a4, &Bs[kk*O2], j*4);
        }
    }
    __syncthreads();

    if constexpr (PHASE == 2){
#pragma unroll
        for (int uu=0; uu<UU2; ++uu)
#pragma unroll
        for (int e=0; e<4; ++e){
            float bb = b2[j*4+64*uu+e];
#pragma unroll
            for (int rr=0; rr<4; ++rr) acc2[rr][uu][e] += bb;
        }
        stats_write<UU2,K,false>(acc2, t, m0, blockIdx.x, Bs, pS, pQ, gmax, gmin);
        return;
    }

    // ---- act2 -> As ([o2=k][row], k<O2) ----
#pragma unroll
    for (int uu=0; uu<UU2; ++uu)
#pragma unroll
    for (int e=0; e<4; ++e){
        int c = j*4 + 64*uu + e;
        float bb = b2[c], scv = sc2[c], shv = sh2[c];
#pragma unroll
        for (int rr=0; rr<4; ++rr)
            As[c*64 + i*4+rr] = fmaxf(0.f, (acc2[rr][uu][e]+bb)*scv + shv);
    }

    // ---- GEMM3 (C=O2, O=O3, W3 stride O2), KS3-k slabs (KS3*O3 = 4096) ----
    constexpr int UU3 = O3/64;
    constexpr int KS3 = 4096/O3;         // 16 for O3=256, 32 for O3=128
    constexpr int QQ3 = KS3/4;
    float acc3[4][UU3][4] = {};
    for (int k0=0; k0<O2; k0+=KS3){
        __syncthreads();   // k0=0: fence act2 As-writes; else: prior Bs reads done
#pragma unroll
        for (int it=0; it<4; ++it){      // 1024 slots = KS3*O3/4
            int slot = t + it*256;
            int o = slot / QQ3, qq = slot % QQ3;
            float4 wv = *(const float4*)(W3 + o*O2 + k0 + qq*4);
            Bs[(qq*4+0)*O3 + o] = wv.x; Bs[(qq*4+1)*O3 + o] = wv.y;
            Bs[(qq*4+2)*O3 + o] = wv.z; Bs[(qq*4+3)*O3 + o] = wv.w;
        }
        __syncthreads();
#pragma unroll 2
        for (int kk=0; kk<KS3; ++kk){
            float4 a4 = *(const float4*)&As[(k0+kk)*64 + i*4];
            fma_tile<UU3>(acc3, a4, &Bs[kk*O3], j*4);
        }
    }
    __syncthreads();

#pragma unroll
    for (int uu=0; uu<UU3; ++uu)
#pragma unroll
    for (int e=0; e<4; ++e){
        float bb = b3[j*4+64*uu+e];
#pragma unroll
        for (int rr=0; rr<4; ++rr) acc3[rr][uu][e] += bb;
    }
    stats_write<UU3,K,true>(acc3, t, m0, blockIdx.x, Bs, pS, pQ, gmax, gmin);
}

// ---------------- finalize BN stats (fp64 accumulation) ----------------
__global__ __launch_bounds__(256) void finalize_d_kernel(const float* __restrict__ pS, const float* __restrict__ pQ,
                                      const float* __restrict__ g, const float* __restrict__ bt,
                                      float* __restrict__ sc, float* __restrict__ sh, int nb, double invM){
    __shared__ double red[512];
    int c = blockIdx.x;
    int O = gridDim.x;
    int t = threadIdx.x;
    double S=0.0, Q=0.0;
    for (int v=t; v<nb; v+=256){ S += (double)pS[(size_t)v*O + c]; Q += (double)pQ[(size_t)v*O + c]; }
    red[t]=S; red[256+t]=Q;
    __syncthreads();
    for (int s=128; s>0; s>>=1){
        if (t<s){ red[t]+=red[t+s]; red[256+t]+=red[256+t+s]; }
        __syncthreads();
    }
    if (t==0){
        double mean = red[0]*invM;
        double var  = red[256]*invM - mean*mean;
        double scale = (double)g[c] / sqrt(var + 1e-5);
        sc[c] = (float)scale;
        sh[c] = (float)((double)bt[c] - mean*scale);
    }
}

// ---------------- BN+relu on pooled extrema -> output (fp32) ----------------
__global__ void final_out_kernel(const float* __restrict__ gmax, const float* __restrict__ gmin,
                                 const float* __restrict__ sc, const float* __restrict__ sh,
                                 float* __restrict__ outp, int O, int logO, int chbase){
    int gid = blockIdx.x*256 + threadIdx.x;   // over 8192*O
    int c  = gid & (O-1);
    int bs = gid >> logO;
    int b = bs >> 10, s = bs & 1023;
    float scale = sc[c];
    float v = (scale >= 0.f) ? gmax[gid] : gmin[gid];
    float r = fmaxf(0.f, scale*v + sh[c]);
    outp[((size_t)(b*640 + chbase + c))*SS + s] = r;
}

__global__ void ws_marker_kernel(float* outp, float wsval){ if (threadIdx.x==0) outp[0] = wsval; }

template<int K, int O1, int O2, int O3>
static void run_branch(const float* ptsT, const float* q, const int* gidx,
                       float* pS, float* pQ, float* gmax, float* gmin,
                       float* sc1, float* sh1, float* sc2, float* sh2, float* sc3, float* sh3,
                       void* const* d_in, int wbase, float* np_out, int chbase, hipStream_t stream)
{
    const int M = BB*SS*K;
    const int nb = M/64;
    auto wp = [&](int jl, int which)->const float* { return (const float*)d_in[2 + (wbase+jl)*4 + which]; };
    const double invM = 1.0 / (double)M;

    fused_mlp<1,K,O1,O2,O3><<<nb,256,0,stream>>>(ptsT,q,gidx,
        wp(0,0),wp(0,1), wp(1,0),wp(1,1), wp(2,0),wp(2,1),
        sc1,sh1, sc2,sh2, pS,pQ, gmax,gmin);
    finalize_d_kernel<<<O1,256,0,stream>>>(pS,pQ, wp(0,2), wp(0,3), sc1, sh1, nb, invM);

    fused_mlp<2,K,O1,O2,O3><<<nb,256,0,stream>>>(ptsT,q,gidx,
        wp(0,0),wp(0,1), wp(1,0),wp(1,1), wp(2,0),wp(2,1),
        sc1,sh1, sc2,sh2, pS,pQ, gmax,gmin);
    finalize_d_kernel<<<O2,256,0,stream>>>(pS,pQ, wp(1,2), wp(1,3), sc2, sh2, nb, invM);

    fused_mlp<3,K,O1,O2,O3><<<nb,256,0,stream>>>(ptsT,q,gidx,
        wp(0,0),wp(0,1), wp(1,0),wp(1,1), wp(2,0),wp(2,1),
        sc1,sh1, sc2,sh2, pS,pQ, gmax,gmin);
    finalize_d_kernel<<<O3,256,0,stream>>>(pS,pQ, wp(2,2), wp(2,3), sc3, sh3, nb, invM);

    final_out_kernel<<<(BB*SS*O3)/256,256,0,stream>>>(gmax,gmin, sc3,sh3, np_out, O3, (O3==256?8:7), chbase);
}

extern "C" void kernel_launch(void* const* d_in, const int* in_sizes, int n_in,
                              void* d_out, int out_size, void* d_ws, size_t ws_size,
                              hipStream_t stream)
{
    const float* xyz = (const float*)d_in[0];
    const float* pts = (const float*)d_in[1];
    float* outp = (float*)d_out;

    char* wsb = (char*)d_ws;
    size_t off = 0;
    auto alloc = [&](size_t bytes) -> void* {
        off = (off + 255) & ~(size_t)255;
        void* p = wsb + off;
        off += bytes;
        return p;
    };
    int*   fps_idx = (int*)  alloc((size_t)BB*SS*4);
    float* q       = (float*)alloc((size_t)BB*SS*3*4);
    int*   idx0    = (int*)  alloc((size_t)BB*SS*16*4);
    int*   idx1    = (int*)  alloc((size_t)BB*SS*32*4);
    int*   idx2    = (int*)  alloc((size_t)BB*SS*64*4);
    float* ptsT    = (float*)alloc((size_t)BB*NN*64*4);
    float* pS      = (float*)alloc((size_t)8192*256*4);
    float* pQ      = (float*)alloc((size_t)8192*256*4);
    float* gmax    = (float*)alloc((size_t)8192*256*4);
    float* gmin    = (float*)alloc((size_t)8192*256*4);
    float* sc1     = (float*)alloc(256*4);
    float* sh1     = (float*)alloc(256*4);
    float* sc2     = (float*)alloc(256*4);
    float* sh2     = (float*)alloc(256*4);
    float* sc3     = (float*)alloc(256*4);
    float* sh3     = (float*)alloc(256*4);

    if (off > ws_size){
        ws_marker_kernel<<<1,64,0,stream>>>(outp, (float)ws_size);
        return;
    }

    build_ptsT_kernel<<<dim3(NN/64, BB), 256, 0, stream>>>(xyz, pts, ptsT);
    fps_kernel<<<BB, 1024, 0, stream>>>(xyz, fps_idx);
    gather_q_kernel<<<32, 256, 0, stream>>>(xyz, fps_idx, q, outp);

    const float r2a = (float)(0.1*0.1);
    const float r2b = (float)(0.2*0.2);
    const float r2c = (float)(0.4*0.4);
    ballquery_kernel<<<2048, 256, 0, stream>>>(xyz, q, idx0, idx1, idx2, r2a, r2b, r2c);

    float* np_out = outp + (size_t)BB*3*SS;
    run_branch<16, 64, 64,128>(ptsT, q, idx0, pS,pQ, gmax,gmin, sc1,sh1,sc2,sh2,sc3,sh3, d_in, 0, np_out,   0, stream);
    run_branch<32,128,128,256>(ptsT, q, idx1, pS,pQ, gmax,gmin, sc1,sh1,sc2,sh2,sc3,sh3, d_in, 3, np_out, 128, stream);
    run_branch<64,128,128,256>(ptsT, q, idx2, pS,pQ, gmax,gmin, sc1,sh1,sc2,sh2,sc3,sh3, d_in, 6, np_out, 384, stream);

    // launch-error telemetry: if any launch was rejected, scribble a decodable
    // marker into out[0] (new_xyz[0,0,0]) -> output-0 absmax reports ~1000+code
    hipError_t e = hipGetLastError();
    if (e != hipSuccess){
        ws_marker_kernel<<<1,64,0,stream>>>(outp, 1000.0f + (float)(int)e);
    }
}

// Round 6
// 5000.012 us; speedup vs baseline: 1.0149x; 1.0149x over previous
//
#include <hip/hip_runtime.h>
#include <stdint.h>

#define BB 8
#define NN 16384
#define SS 1024

// ---------------- FPS v2: one block per batch, 512 thr, single-barrier iterations ----------------
// Exact np fp32 semantics: d=(dx*dx+dy*dy)+dz*dz contract-off; np.minimum; argmax first-max tie-break.
__global__ __launch_bounds__(512) void fps_kernel(const float* __restrict__ xyz, int* __restrict__ fps_idx){
#pragma clang fp contract(off)
    int b = blockIdx.x;
    int t = threadIdx.x;
    const float* xb = xyz + (size_t)b*3*NN;
    float px[32], py[32], pz[32], dd[32];
#pragma unroll
    for (int j=0;j<32;++j){
        int n = t + j*512;
        px[j] = xb[n];
        py[j] = xb[NN+n];
        pz[j] = xb[2*NN+n];
        dd[j] = 1e10f;
    }
    __shared__ float rv[2][8];
    __shared__ int   rn[2][8];
    int lane = t & 63, wid = t >> 6;
    int far = 0;
    int* outp = fps_idx + b*SS;
    float cx = xb[0], cy = xb[NN], cz = xb[2*NN];
    for (int it=0; it<SS; ++it){
        if (t==0) outp[it] = far;
        float bestv = -1.0f; int bestn = 0x7fffffff;
#pragma unroll
        for (int j=0;j<32;++j){
            float dx = px[j]-cx, dy = py[j]-cy, dz = pz[j]-cz;
            float d = dx*dx + dy*dy;
            d = d + dz*dz;
            float dm = dd[j] < d ? dd[j] : d;   // np.minimum
            dd[j] = dm;
            if (dm > bestv){ bestv = dm; bestn = t + j*512; }  // strict > keeps lowest n in-thread
        }
        // wave reduce (64 lanes), tie -> lower index
#pragma unroll
        for (int off=32; off>0; off>>=1){
            float ov = __shfl_down(bestv, off);
            int   on = __shfl_down(bestn, off);
            if (ov > bestv || (ov == bestv && on < bestn)){ bestv = ov; bestn = on; }
        }
        int pb = it & 1;                       // double-buffered partials -> ONE barrier/iter
        if (lane == 0){ rv[pb][wid] = bestv; rn[pb][wid] = bestn; }
        __syncthreads();
        // every wave redundantly reduces the 8 partials; no second barrier, no LDS broadcast
        float v2 = (lane < 8) ? rv[pb][lane] : -1.0f;
        int   n2 = (lane < 8) ? rn[pb][lane] : 0x7fffffff;
#pragma unroll
        for (int off=4; off>0; off>>=1){
            float ov = __shfl_down(v2, off);
            int   on = __shfl_down(n2, off);
            if (ov > v2 || (ov == v2 && on < n2)){ v2 = ov; n2 = on; }
        }
        far = __shfl(n2, 0);
        cx = xb[far]; cy = xb[NN+far]; cz = xb[2*NN+far];
    }
}

// ---------------- gather query coords + write new_xyz output (fp32) ----------------
__global__ void gather_q_kernel(const float* __restrict__ xyz, const int* __restrict__ fps_idx,
                                float* __restrict__ q, float* __restrict__ out_xyz){
    int i = blockIdx.x*blockDim.x + threadIdx.x;
    if (i >= BB*SS) return;
    int b = i >> 10, s = i & 1023;
    int idx = fps_idx[i];
    for (int c=0;c<3;++c){
        float v = xyz[((size_t)b*3+c)*NN + idx];
        q[i*3+c] = v;
        out_xyz[((size_t)b*3+c)*SS + s] = v;
    }
}

// ---------------- build ptsT[b][n][64]: c0..2 = xyz, c3..63 = points ----------------
__global__ __launch_bounds__(256) void build_ptsT_kernel(const float* __restrict__ xyz, const float* __restrict__ pts,
                                                         float* __restrict__ ptsT){
    __shared__ float tile[64][65];
    int b = blockIdx.y;
    int n0 = blockIdx.x * 64;
    int t = threadIdx.x;
    int ln = t & 63, cr = t >> 6;
    for (int c = cr; c < 64; c += 4){
        float v;
        if (c < 3) v = xyz[((size_t)b*3 + c)*NN + n0 + ln];
        else       v = pts[((size_t)b*61 + (c-3))*NN + n0 + ln];
        tile[ln][c] = v;
    }
    __syncthreads();
    int lc = t & 63, nr = t >> 6;
    for (int n = nr; n < 64; n += 4){
        ptsT[((size_t)b*NN + n0 + n)*64 + lc] = tile[n][lc];
    }
}

// ---------------- ball query: one wave per (b,s), 3 radii fused ----------------
__global__ __launch_bounds__(256) void ballquery_kernel(const float* __restrict__ xyz, const float* __restrict__ q,
        int* __restrict__ idx0, int* __restrict__ idx1, int* __restrict__ idx2,
        float r2a, float r2b, float r2c){
#pragma clang fp contract(off)
    __shared__ int lds[4][112];
    int t = threadIdx.x;
    int w = t >> 6, lane = t & 63;
    int qi = blockIdx.x*4 + w;           // < 8192
    int b = qi >> 10;
    const float* xb = xyz + (size_t)b*3*NN;
    float qx = q[qi*3], qy = q[qi*3+1], qz = q[qi*3+2];
    float qn = qx*qx + qy*qy; qn = qn + qz*qz;
    int* l0 = lds[w];
    int* l1 = l0 + 16;
    int* l2 = l0 + 48;
    l0[lane] = 0;
    if (lane < 48) l0[64+lane] = 0;
    int c0=0, c1=0, c2=0;
    uint64_t below = (1ull << lane) - 1ull;
    for (int ch=0; ch<256; ++ch){
        int n = ch*64 + lane;
        float x = xb[n], y = xb[NN+n], z = xb[2*NN+n];
        float dn = x*x + y*y; dn = dn + z*z;
        float dot = qx*x + qy*y; dot = dot + qz*z;
        float d = -2.0f*dot + qn;
        d = d + dn;
        bool o0 = d <= r2a, o1 = d <= r2b, o2 = d <= r2c;
        uint64_t m0 = __ballot(o0), m1 = __ballot(o1), m2 = __ballot(o2);
        if (c0 < 16){
            int p = c0 + (int)__popcll(m0 & below);
            if (o0 && p < 16) l0[p] = n;
            c0 += (int)__popcll(m0); if (c0 > 16) c0 = 16;
        }
        if (c1 < 32){
            int p = c1 + (int)__popcll(m1 & below);
            if (o1 && p < 32) l1[p] = n;
            c1 += (int)__popcll(m1); if (c1 > 32) c1 = 32;
        }
        if (c2 < 64){
            int p = c2 + (int)__popcll(m2 & below);
            if (o2 && p < 64) l2[p] = n;
            c2 += (int)__popcll(m2); if (c2 > 64) c2 = 64;
        }
        if (c0>=16 && c1>=32 && c2>=64) break;
    }
    __syncthreads();
    int f0 = l0[0], f1 = l1[0], f2 = l2[0];
    if (lane >= c0 && lane < 16) l0[lane] = f0;
    if (lane >= c1 && lane < 32) l1[lane] = f1;
    if (lane >= c2)              l2[lane] = f2;
    __syncthreads();
    if (lane < 16) idx0[(size_t)qi*16 + lane] = l0[lane];
    if (lane < 32) idx1[(size_t)qi*32 + lane] = l1[lane];
    idx2[(size_t)qi*64 + lane] = l2[lane];
}

// ---------------- MAC helper ----------------
template<int UU>
__device__ __forceinline__ void fma_tile(float (&acc)[4][UU][4], float4 a4, const float* bsrow, int jbase){
#pragma unroll
    for (int uu=0; uu<UU; ++uu){
        float4 b4 = *(const float4*)(bsrow + jbase + 64*uu);
        acc[0][uu][0]+=a4.x*b4.x; acc[0][uu][1]+=a4.x*b4.y; acc[0][uu][2]+=a4.x*b4.z; acc[0][uu][3]+=a4.x*b4.w;
        acc[1][uu][0]+=a4.y*b4.x; acc[1][uu][1]+=a4.y*b4.y; acc[1][uu][2]+=a4.y*b4.z; acc[1][uu][3]+=a4.y*b4.w;
        acc[2][uu][0]+=a4.z*b4.x; acc[2][uu][1]+=a4.z*b4.y; acc[2][uu][2]+=a4.z*b4.z; acc[2][uu][3]+=a4.z*b4.w;
        acc[3][uu][0]+=a4.w*b4.x; acc[3][uu][1]+=a4.w*b4.y; acc[3][uu][2]+=a4.w*b4.z; acc[3][uu][3]+=a4.w*b4.w;
    }
}

// ---------------- stats / extrema epilogue helper ----------------
template<int UU, int K, bool EXT>
__device__ __forceinline__ void stats_write(float (&z)[4][UU][4], int t, int m0, int blk,
    float* scr, float* __restrict__ pS, float* __restrict__ pQ,
    float* __restrict__ gmax, float* __restrict__ gmin)
{
    constexpr int O = UU*64;
    int j = t & 15;
    float s1[UU][4], s2[UU][4], mx[UU][4], mn[UU][4];
#pragma unroll
    for (int uu=0; uu<UU; ++uu)
#pragma unroll
    for (int e=0; e<4; ++e){
        float v0=z[0][uu][e], v1=z[1][uu][e], v2=z[2][uu][e], v3=z[3][uu][e];
        s1[uu][e]=(v0+v1)+(v2+v3);
        s2[uu][e]=(v0*v0+v1*v1)+(v2*v2+v3*v3);
        if (EXT){
            mx[uu][e]=fmaxf(fmaxf(v0,v1),fmaxf(v2,v3));
            mn[uu][e]=fminf(fminf(v0,v1),fminf(v2,v3));
        }
    }
#pragma unroll
    for (int uu=0; uu<UU; ++uu)
#pragma unroll
    for (int e=0; e<4; ++e){
        s1[uu][e] += __shfl_xor(s1[uu][e],16); s1[uu][e] += __shfl_xor(s1[uu][e],32);
        s2[uu][e] += __shfl_xor(s2[uu][e],16); s2[uu][e] += __shfl_xor(s2[uu][e],32);
        if (EXT){
            mx[uu][e] = fmaxf(mx[uu][e], __shfl_xor(mx[uu][e],16)); mx[uu][e] = fmaxf(mx[uu][e], __shfl_xor(mx[uu][e],32));
            mn[uu][e] = fminf(mn[uu][e], __shfl_xor(mn[uu][e],16)); mn[uu][e] = fminf(mn[uu][e], __shfl_xor(mn[uu][e],32));
        }
    }
    int wv = t >> 6;
    if ((t & 63) < 16){
#pragma unroll
        for (int uu=0; uu<UU; ++uu)
#pragma unroll
        for (int e=0; e<4; ++e){
            int c = j*4 + 64*uu + e;
            scr[0*4*O + wv*O + c] = s1[uu][e];
            scr[1*4*O + wv*O + c] = s2[uu][e];
            if (EXT){
                scr[2*4*O + wv*O + c] = mx[uu][e];
                scr[3*4*O + wv*O + c] = mn[uu][e];
            }
        }
    }
    __syncthreads();
    for (int c=t; c<O; c+=256){
        float S = ((scr[c] + scr[O+c]) + (scr[2*O+c] + scr[3*O+c]));
        float Q = ((scr[4*O+c] + scr[5*O+c]) + (scr[6*O+c] + scr[7*O+c]));
        pS[(size_t)blk*O + c] = S;
        pQ[(size_t)blk*O + c] = Q;
        if (EXT){
            constexpr int G  = 64/K;
            constexpr int WG = K/16;
#pragma unroll
            for (int g=0; g<G; ++g){
                float M1 = scr[2*4*O + (g*WG)*O + c];
                float M2 = scr[3*4*O + (g*WG)*O + c];
#pragma unroll
                for (int ww=1; ww<WG; ++ww){
                    M1 = fmaxf(M1, scr[2*4*O + (g*WG+ww)*O + c]);
                    M2 = fminf(M2, scr[3*4*O + (g*WG+ww)*O + c]);
                }
                int bs = m0/K + g;
                gmax[(size_t)bs*O + c] = M1;
                gmin[(size_t)bs*O + c] = M2;
            }
        }
    }
}

// ---------------- fused MLP phases: block = 64 rows x full width, no z materialization ----------------
template<int PHASE, int K, int O1, int O2, int O3>
__global__ __launch_bounds__(256) void fused_mlp(
    const float* __restrict__ ptsT, const float* __restrict__ q, const int* __restrict__ gidx,
    const float* __restrict__ W1, const float* __restrict__ b1,
    const float* __restrict__ W2, const float* __restrict__ b2,
    const float* __restrict__ W3, const float* __restrict__ b3,
    const float* __restrict__ sc1, const float* __restrict__ sh1,
    const float* __restrict__ sc2, const float* __restrict__ sh2,
    float* __restrict__ pS, float* __restrict__ pQ,
    float* __restrict__ gmax, float* __restrict__ gmin)
{
    __shared__ float As[8192];   // 32 KB: [k][row], k up to 128
    __shared__ float Bs[4096];   // 16 KB: weight k-slabs [k][o] / stats scratch
    int t = threadIdx.x;
    int m0 = blockIdx.x * 64;
    int j = t & 15, i = t >> 4;

    // ---- gather A0 (64 rows x 64 ch) ----
    {
        int r = t >> 2, q4 = t & 3;
        int m = m0 + r;
        int idx = gidx[m];
        int bs = m / K;
        int b = bs >> 10;
        const float* base = ptsT + ((size_t)b*NN + idx)*64;
        float qx=0.f, qy=0.f, qz=0.f;
        if (q4 == 0){ qx = q[bs*3]; qy = q[bs*3+1]; qz = q[bs*3+2]; }
#pragma unroll
        for (int ii=0; ii<4; ++ii){
            int c0 = q4*16 + ii*4;
            float4 v = *(const float4*)(base + c0);
            if (q4==0 && ii==0){ v.x -= qx; v.y -= qy; v.z -= qz; }
            As[(c0+0)*64 + r] = v.x; As[(c0+1)*64 + r] = v.y;
            As[(c0+2)*64 + r] = v.z; As[(c0+3)*64 + r] = v.w;
        }
    }

    // ---- GEMM1 (C=64, O=O1, W1 stride 64), 32-k slabs ----
    constexpr int UU1 = O1/64;
    float acc1[4][UU1][4] = {};
    for (int k0=0; k0<64; k0+=32){
        __syncthreads();
#pragma unroll
        for (int it=0; it<O1/32; ++it){
            int slot = t + it*256;
            int o = slot >> 3, qq = slot & 7;
            float4 wv = *(const float4*)(W1 + o*64 + k0 + qq*4);
            Bs[(qq*4+0)*O1 + o] = wv.x; Bs[(qq*4+1)*O1 + o] = wv.y;
            Bs[(qq*4+2)*O1 + o] = wv.z; Bs[(qq*4+3)*O1 + o] = wv.w;
        }
        __syncthreads();
#pragma unroll 4
        for (int kk=0; kk<32; ++kk){
            float4 a4 = *(const float4*)&As[(k0+kk)*64 + i*4];
            fma_tile<UU1>(acc1, a4, &Bs[kk*O1], j*4);
        }
    }
    __syncthreads();

    if constexpr (PHASE == 1){
#pragma unroll
        for (int uu=0; uu<UU1; ++uu)
#pragma unroll
        for (int e=0; e<4; ++e){
            float bb = b1[j*4 + 64*uu + e];
#pragma unroll
            for (int rr=0; rr<4; ++rr) acc1[rr][uu][e] += bb;
        }
        stats_write<UU1,K,false>(acc1, t, m0, blockIdx.x, Bs, pS, pQ, gmax, gmin);
        return;
    }

    // ---- act1 -> As ([o1=k][row], k<O1) ----
#pragma unroll
    for (int uu=0; uu<UU1; ++uu)
#pragma unroll
    for (int e=0; e<4; ++e){
        int c = j*4 + 64*uu + e;
        float bb = b1[c], scv = sc1[c], shv = sh1[c];
#pragma unroll
        for (int rr=0; rr<4; ++rr)
            As[c*64 + i*4+rr] = fmaxf(0.f, (acc1[rr][uu][e]+bb)*scv + shv);
    }

    // ---- GEMM2 (C=O1, O=O2, W2 stride O1), 32-k slabs ----
    constexpr int UU2 = O2/64;
    float acc2[4][UU2][4] = {};
    for (int k0=0; k0<O1; k0+=32){
        __syncthreads();
#pragma unroll
        for (int it=0; it<O2/32; ++it){
            int slot = t + it*256;
            int o = slot >> 3, qq = slot & 7;
            float4 wv = *(const float4*)(W2 + o*O1 + k0 + qq*4);
            Bs[(qq*4+0)*O2 + o] = wv.x; Bs[(qq*4+1)*O2 + o] = wv.y;
            Bs[(qq*4+2)*O2 + o] = wv.z; Bs[(qq*4+3)*O2 + o] = wv.w;
        }
        __syncthreads();
#pragma unroll 4
        for (int kk=0; kk<32; ++kk){
            float4 a4 = *(const float4*)&As[(k0+kk)*64 + i*4];
            fma_tile<UU2>(acc2, a4, &Bs[kk*O2], j*4);
        }
    }
    __syncthreads();

    if constexpr (PHASE == 2){
#pragma unroll
        for (int uu=0; uu<UU2; ++uu)
#pragma unroll
        for (int e=0; e<4; ++e){
            float bb = b2[j*4+64*uu+e];
#pragma unroll
            for (int rr=0; rr<4; ++rr) acc2[rr][uu][e] += bb;
        }
        stats_write<UU2,K,false>(acc2, t, m0, blockIdx.x, Bs, pS, pQ, gmax, gmin);
        return;
    }

    // ---- act2 -> As ([o2=k][row], k<O2) ----
#pragma unroll
    for (int uu=0; uu<UU2; ++uu)
#pragma unroll
    for (int e=0; e<4; ++e){
        int c = j*4 + 64*uu + e;
        float bb = b2[c], scv = sc2[c], shv = sh2[c];
#pragma unroll
        for (int rr=0; rr<4; ++rr)
            As[c*64 + i*4+rr] = fmaxf(0.f, (acc2[rr][uu][e]+bb)*scv + shv);
    }

    // ---- GEMM3 (C=O2, O=O3, W3 stride O2), KS3-k slabs (KS3*O3 = 4096) ----
    constexpr int UU3 = O3/64;
    constexpr int KS3 = 4096/O3;
    constexpr int QQ3 = KS3/4;
    float acc3[4][UU3][4] = {};
    for (int k0=0; k0<O2; k0+=KS3){
        __syncthreads();
#pragma unroll
        for (int it=0; it<4; ++it){
            int slot = t + it*256;
            int o = slot / QQ3, qq = slot % QQ3;
            float4 wv = *(const float4*)(W3 + o*O2 + k0 + qq*4);
            Bs[(qq*4+0)*O3 + o] = wv.x; Bs[(qq*4+1)*O3 + o] = wv.y;
            Bs[(qq*4+2)*O3 + o] = wv.z; Bs[(qq*4+3)*O3 + o] = wv.w;
        }
        __syncthreads();
#pragma unroll 2
        for (int kk=0; kk<KS3; ++kk){
            float4 a4 = *(const float4*)&As[(k0+kk)*64 + i*4];
            fma_tile<UU3>(acc3, a4, &Bs[kk*O3], j*4);
        }
    }
    __syncthreads();

#pragma unroll
    for (int uu=0; uu<UU3; ++uu)
#pragma unroll
    for (int e=0; e<4; ++e){
        float bb = b3[j*4+64*uu+e];
#pragma unroll
        for (int rr=0; rr<4; ++rr) acc3[rr][uu][e] += bb;
    }
    stats_write<UU3,K,true>(acc3, t, m0, blockIdx.x, Bs, pS, pQ, gmax, gmin);
}

// ---------------- finalize BN stats (fp64 accumulation) ----------------
__global__ __launch_bounds__(256) void finalize_d_kernel(const float* __restrict__ pS, const float* __restrict__ pQ,
                                      const float* __restrict__ g, const float* __restrict__ bt,
                                      float* __restrict__ sc, float* __restrict__ sh, int nb, double invM){
    __shared__ double red[512];
    int c = blockIdx.x;
    int O = gridDim.x;
    int t = threadIdx.x;
    double S=0.0, Q=0.0;
    for (int v=t; v<nb; v+=256){ S += (double)pS[(size_t)v*O + c]; Q += (double)pQ[(size_t)v*O + c]; }
    red[t]=S; red[256+t]=Q;
    __syncthreads();
    for (int s=128; s>0; s>>=1){
        if (t<s){ red[t]+=red[t+s]; red[256+t]+=red[256+t+s]; }
        __syncthreads();
    }
    if (t==0){
        double mean = red[0]*invM;
        double var  = red[256]*invM - mean*mean;
        double scale = (double)g[c] / sqrt(var + 1e-5);
        sc[c] = (float)scale;
        sh[c] = (float)((double)bt[c] - mean*scale);
    }
}

// ---------------- BN+relu on pooled extrema -> output (fp32) ----------------
__global__ void final_out_kernel(const float* __restrict__ gmax, const float* __restrict__ gmin,
                                 const float* __restrict__ sc, const float* __restrict__ sh,
                                 float* __restrict__ outp, int O, int logO, int chbase){
    int gid = blockIdx.x*256 + threadIdx.x;   // over 8192*O
    int c  = gid & (O-1);
    int bs = gid >> logO;
    int b = bs >> 10, s = bs & 1023;
    float scale = sc[c];
    float v = (scale >= 0.f) ? gmax[gid] : gmin[gid];
    float r = fmaxf(0.f, scale*v + sh[c]);
    outp[((size_t)(b*640 + chbase + c))*SS + s] = r;
}

__global__ void ws_marker_kernel(float* outp, float wsval){ if (threadIdx.x==0) outp[0] = wsval; }

template<int K, int O1, int O2, int O3>
static void run_branch(const float* ptsT, const float* q, const int* gidx,
                       float* pS, float* pQ, float* gmax, float* gmin,
                       float* sc1, float* sh1, float* sc2, float* sh2, float* sc3, float* sh3,
                       void* const* d_in, int wbase, float* np_out, int chbase, hipStream_t stream)
{
    const int M = BB*SS*K;
    const int nb = M/64;
    auto wp = [&](int jl, int which)->const float* { return (const float*)d_in[2 + (wbase+jl)*4 + which]; };
    const double invM = 1.0 / (double)M;

    fused_mlp<1,K,O1,O2,O3><<<nb,256,0,stream>>>(ptsT,q,gidx,
        wp(0,0),wp(0,1), wp(1,0),wp(1,1), wp(2,0),wp(2,1),
        sc1,sh1, sc2,sh2, pS,pQ, gmax,gmin);
    finalize_d_kernel<<<O1,256,0,stream>>>(pS,pQ, wp(0,2), wp(0,3), sc1, sh1, nb, invM);

    fused_mlp<2,K,O1,O2,O3><<<nb,256,0,stream>>>(ptsT,q,gidx,
        wp(0,0),wp(0,1), wp(1,0),wp(1,1), wp(2,0),wp(2,1),
        sc1,sh1, sc2,sh2, pS,pQ, gmax,gmin);
    finalize_d_kernel<<<O2,256,0,stream>>>(pS,pQ, wp(1,2), wp(1,3), sc2, sh2, nb, invM);

    fused_mlp<3,K,O1,O2,O3><<<nb,256,0,stream>>>(ptsT,q,gidx,
        wp(0,0),wp(0,1), wp(1,0),wp(1,1), wp(2,0),wp(2,1),
        sc1,sh1, sc2,sh2, pS,pQ, gmax,gmin);
    finalize_d_kernel<<<O3,256,0,stream>>>(pS,pQ, wp(2,2), wp(2,3), sc3, sh3, nb, invM);

    final_out_kernel<<<(BB*SS*O3)/256,256,0,stream>>>(gmax,gmin, sc3,sh3, np_out, O3, (O3==256?8:7), chbase);
}

extern "C" void kernel_launch(void* const* d_in, const int* in_sizes, int n_in,
                              void* d_out, int out_size, void* d_ws, size_t ws_size,
                              hipStream_t stream)
{
    const float* xyz = (const float*)d_in[0];
    const float* pts = (const float*)d_in[1];
    float* outp = (float*)d_out;

    char* wsb = (char*)d_ws;
    size_t off = 0;
    auto alloc = [&](size_t bytes) -> void* {
        off = (off + 255) & ~(size_t)255;
        void* p = wsb + off;
        off += bytes;
        return p;
    };
    int*   fps_idx = (int*)  alloc((size_t)BB*SS*4);
    float* q       = (float*)alloc((size_t)BB*SS*3*4);
    int*   idx0    = (int*)  alloc((size_t)BB*SS*16*4);
    int*   idx1    = (int*)  alloc((size_t)BB*SS*32*4);
    int*   idx2    = (int*)  alloc((size_t)BB*SS*64*4);
    float* ptsT    = (float*)alloc((size_t)BB*NN*64*4);
    float* pS      = (float*)alloc((size_t)8192*256*4);
    float* pQ      = (float*)alloc((size_t)8192*256*4);
    float* gmax    = (float*)alloc((size_t)8192*256*4);
    float* gmin    = (float*)alloc((size_t)8192*256*4);
    float* sc1     = (float*)alloc(256*4);
    float* sh1     = (float*)alloc(256*4);
    float* sc2     = (float*)alloc(256*4);
    float* sh2     = (float*)alloc(256*4);
    float* sc3     = (float*)alloc(256*4);
    float* sh3     = (float*)alloc(256*4);

    if (off > ws_size){
        ws_marker_kernel<<<1,64,0,stream>>>(outp, (float)ws_size);
        return;
    }

    build_ptsT_kernel<<<dim3(NN/64, BB), 256, 0, stream>>>(xyz, pts, ptsT);
    fps_kernel<<<BB, 512, 0, stream>>>(xyz, fps_idx);
    gather_q_kernel<<<32, 256, 0, stream>>>(xyz, fps_idx, q, outp);

    const float r2a = (float)(0.1*0.1);
    const float r2b = (float)(0.2*0.2);
    const float r2c = (float)(0.4*0.4);
    ballquery_kernel<<<2048, 256, 0, stream>>>(xyz, q, idx0, idx1, idx2, r2a, r2b, r2c);

    float* np_out = outp + (size_t)BB*3*SS;
    run_branch<16, 64, 64,128>(ptsT, q, idx0, pS,pQ, gmax,gmin, sc1,sh1,sc2,sh2,sc3,sh3, d_in, 0, np_out,   0, stream);
    run_branch<32,128,128,256>(ptsT, q, idx1, pS,pQ, gmax,gmin, sc1,sh1,sc2,sh2,sc3,sh3, d_in, 3, np_out, 128, stream);
    run_branch<64,128,128,256>(ptsT, q, idx2, pS,pQ, gmax,gmin, sc1,sh1,sc2,sh2,sc3,sh3, d_in, 6, np_out, 384, stream);

    hipError_t e = hipGetLastError();
    if (e != hipSuccess){
        ws_marker_kernel<<<1,64,0,stream>>>(outp, 1000.0f + (float)(int)e);
    }
}

// Round 7
// 4562.249 us; speedup vs baseline: 1.1123x; 1.0960x over previous
//
#include <hip/hip_runtime.h>
#include <stdint.h>

#define BB 8
#define NN 16384
#define SS 1024

typedef unsigned short u16;
static __device__ __forceinline__ float bf2f(u16 u){
    union { uint32_t u; float f; } v; v.u = ((uint32_t)u) << 16; return v.f;
}
static __device__ __forceinline__ u16 f2bf(float f){
    union { float f; uint32_t u; } v; v.f = f;
    return (u16)((v.u + 0x7FFFu + ((v.u >> 16) & 1u)) >> 16);
}

// ---------------- FPS: one block per batch, 512 thr; (512,2) => VGPR cap 256, arrays stay in regs ----------------
__global__ __launch_bounds__(512, 2) void fps_kernel(const float* __restrict__ xyz, int* __restrict__ fps_idx){
#pragma clang fp contract(off)
    int b = blockIdx.x;
    int t = threadIdx.x;
    const float* xb = xyz + (size_t)b*3*NN;
    float px[32], py[32], pz[32], dd[32];
#pragma unroll
    for (int j=0;j<32;++j){
        int n = t + j*512;
        px[j] = xb[n];
        py[j] = xb[NN+n];
        pz[j] = xb[2*NN+n];
        dd[j] = 1e10f;
    }
    __shared__ float rv[2][8];
    __shared__ int   rn[2][8];
    int lane = t & 63, wid = t >> 6;
    int far = 0;
    int* outp = fps_idx + b*SS;
    float cx = xb[0], cy = xb[NN], cz = xb[2*NN];
    for (int it=0; it<SS; ++it){
        if (t==0) outp[it] = far;
        float bestv = -1.0f; int bestn = 0x7fffffff;
#pragma unroll
        for (int j=0;j<32;++j){
            float dx = px[j]-cx, dy = py[j]-cy, dz = pz[j]-cz;
            float d = dx*dx + dy*dy;
            d = d + dz*dz;
            float dm = dd[j] < d ? dd[j] : d;   // np.minimum
            dd[j] = dm;
            if (dm > bestv){ bestv = dm; bestn = t + j*512; }  // strict > keeps lowest n in-thread
        }
#pragma unroll
        for (int off=32; off>0; off>>=1){
            float ov = __shfl_down(bestv, off);
            int   on = __shfl_down(bestn, off);
            if (ov > bestv || (ov == bestv && on < bestn)){ bestv = ov; bestn = on; }
        }
        int pb = it & 1;
        if (lane == 0){ rv[pb][wid] = bestv; rn[pb][wid] = bestn; }
        __syncthreads();
        float v2 = (lane < 8) ? rv[pb][lane] : -1.0f;
        int   n2 = (lane < 8) ? rn[pb][lane] : 0x7fffffff;
#pragma unroll
        for (int off=4; off>0; off>>=1){
            float ov = __shfl_down(v2, off);
            int   on = __shfl_down(n2, off);
            if (ov > v2 || (ov == v2 && on < n2)){ v2 = ov; n2 = on; }
        }
        far = __shfl(n2, 0);
        cx = xb[far]; cy = xb[NN+far]; cz = xb[2*NN+far];
    }
}

// ---------------- gather query coords + write new_xyz output (fp32) ----------------
__global__ void gather_q_kernel(const float* __restrict__ xyz, const int* __restrict__ fps_idx,
                                float* __restrict__ q, float* __restrict__ out_xyz){
    int i = blockIdx.x*blockDim.x + threadIdx.x;
    if (i >= BB*SS) return;
    int b = i >> 10, s = i & 1023;
    int idx = fps_idx[i];
    for (int c=0;c<3;++c){
        float v = xyz[((size_t)b*3+c)*NN + idx];
        q[i*3+c] = v;
        out_xyz[((size_t)b*3+c)*SS + s] = v;
    }
}

// ---------------- build ptsT[b][n][64]: c0..2 = xyz, c3..63 = points ----------------
__global__ __launch_bounds__(256) void build_ptsT_kernel(const float* __restrict__ xyz, const float* __restrict__ pts,
                                                         float* __restrict__ ptsT){
    __shared__ float tile[64][65];
    int b = blockIdx.y;
    int n0 = blockIdx.x * 64;
    int t = threadIdx.x;
    int ln = t & 63, cr = t >> 6;
    for (int c = cr; c < 64; c += 4){
        float v;
        if (c < 3) v = xyz[((size_t)b*3 + c)*NN + n0 + ln];
        else       v = pts[((size_t)b*61 + (c-3))*NN + n0 + ln];
        tile[ln][c] = v;
    }
    __syncthreads();
    int lc = t & 63, nr = t >> 6;
    for (int n = nr; n < 64; n += 4){
        ptsT[((size_t)b*NN + n0 + n)*64 + lc] = tile[n][lc];
    }
}

// ---------------- ball query: one wave per (b,s), 3 radii fused ----------------
__global__ __launch_bounds__(256) void ballquery_kernel(const float* __restrict__ xyz, const float* __restrict__ q,
        int* __restrict__ idx0, int* __restrict__ idx1, int* __restrict__ idx2,
        float r2a, float r2b, float r2c){
#pragma clang fp contract(off)
    __shared__ int lds[4][112];
    int t = threadIdx.x;
    int w = t >> 6, lane = t & 63;
    int qi = blockIdx.x*4 + w;           // < 8192
    int b = qi >> 10;
    const float* xb = xyz + (size_t)b*3*NN;
    float qx = q[qi*3], qy = q[qi*3+1], qz = q[qi*3+2];
    float qn = qx*qx + qy*qy; qn = qn + qz*qz;
    int* l0 = lds[w];
    int* l1 = l0 + 16;
    int* l2 = l0 + 48;
    l0[lane] = 0;
    if (lane < 48) l0[64+lane] = 0;
    int c0=0, c1=0, c2=0;
    uint64_t below = (1ull << lane) - 1ull;
    for (int ch=0; ch<256; ++ch){
        int n = ch*64 + lane;
        float x = xb[n], y = xb[NN+n], z = xb[2*NN+n];
        float dn = x*x + y*y; dn = dn + z*z;
        float dot = qx*x + qy*y; dot = dot + qz*z;
        float d = -2.0f*dot + qn;
        d = d + dn;
        bool o0 = d <= r2a, o1 = d <= r2b, o2 = d <= r2c;
        uint64_t m0 = __ballot(o0), m1 = __ballot(o1), m2 = __ballot(o2);
        if (c0 < 16){
            int p = c0 + (int)__popcll(m0 & below);
            if (o0 && p < 16) l0[p] = n;
            c0 += (int)__popcll(m0); if (c0 > 16) c0 = 16;
        }
        if (c1 < 32){
            int p = c1 + (int)__popcll(m1 & below);
            if (o1 && p < 32) l1[p] = n;
            c1 += (int)__popcll(m1); if (c1 > 32) c1 = 32;
        }
        if (c2 < 64){
            int p = c2 + (int)__popcll(m2 & below);
            if (o2 && p < 64) l2[p] = n;
            c2 += (int)__popcll(m2); if (c2 > 64) c2 = 64;
        }
        if (c0>=16 && c1>=32 && c2>=64) break;
    }
    __syncthreads();
    int f0 = l0[0], f1 = l1[0], f2 = l2[0];
    if (lane >= c0 && lane < 16) l0[lane] = f0;
    if (lane >= c1 && lane < 32) l1[lane] = f1;
    if (lane >= c2)              l2[lane] = f2;
    __syncthreads();
    if (lane < 16) idx0[(size_t)qi*16 + lane] = l0[lane];
    if (lane < 32) idx1[(size_t)qi*32 + lane] = l1[lane];
    idx2[(size_t)qi*64 + lane] = l2[lane];
}

// ---------------- MAC helper ----------------
template<int UU>
__device__ __forceinline__ void fma_tile(float (&acc)[4][UU][4], float4 a4, const float* bsrow, int jbase){
#pragma unroll
    for (int uu=0; uu<UU; ++uu){
        float4 b4 = *(const float4*)(bsrow + jbase + 64*uu);
        acc[0][uu][0]+=a4.x*b4.x; acc[0][uu][1]+=a4.x*b4.y; acc[0][uu][2]+=a4.x*b4.z; acc[0][uu][3]+=a4.x*b4.w;
        acc[1][uu][0]+=a4.y*b4.x; acc[1][uu][1]+=a4.y*b4.y; acc[1][uu][2]+=a4.y*b4.z; acc[1][uu][3]+=a4.y*b4.w;
        acc[2][uu][0]+=a4.z*b4.x; acc[2][uu][1]+=a4.z*b4.y; acc[2][uu][2]+=a4.z*b4.z; acc[2][uu][3]+=a4.z*b4.w;
        acc[3][uu][0]+=a4.w*b4.x; acc[3][uu][1]+=a4.w*b4.y; acc[3][uu][2]+=a4.w*b4.z; acc[3][uu][3]+=a4.w*b4.w;
    }
}

// ---------------- stats / extrema epilogue helper ----------------
template<int UU, int K, bool EXT>
__device__ __forceinline__ void stats_write(float (&z)[4][UU][4], int t, int m0, int blk,
    float* scr, float* __restrict__ pS, float* __restrict__ pQ,
    float* __restrict__ gmax, float* __restrict__ gmin)
{
    constexpr int O = UU*64;
    int j = t & 15;
    float s1[UU][4], s2[UU][4], mx[UU][4], mn[UU][4];
#pragma unroll
    for (int uu=0; uu<UU; ++uu)
#pragma unroll
    for (int e=0; e<4; ++e){
        float v0=z[0][uu][e], v1=z[1][uu][e], v2=z[2][uu][e], v3=z[3][uu][e];
        s1[uu][e]=(v0+v1)+(v2+v3);
        s2[uu][e]=(v0*v0+v1*v1)+(v2*v2+v3*v3);
        if (EXT){
            mx[uu][e]=fmaxf(fmaxf(v0,v1),fmaxf(v2,v3));
            mn[uu][e]=fminf(fminf(v0,v1),fminf(v2,v3));
        }
    }
#pragma unroll
    for (int uu=0; uu<UU; ++uu)
#pragma unroll
    for (int e=0; e<4; ++e){
        s1[uu][e] += __shfl_xor(s1[uu][e],16); s1[uu][e] += __shfl_xor(s1[uu][e],32);
        s2[uu][e] += __shfl_xor(s2[uu][e],16); s2[uu][e] += __shfl_xor(s2[uu][e],32);
        if (EXT){
            mx[uu][e] = fmaxf(mx[uu][e], __shfl_xor(mx[uu][e],16)); mx[uu][e] = fmaxf(mx[uu][e], __shfl_xor(mx[uu][e],32));
            mn[uu][e] = fminf(mn[uu][e], __shfl_xor(mn[uu][e],16)); mn[uu][e] = fminf(mn[uu][e], __shfl_xor(mn[uu][e],32));
        }
    }
    int wv = t >> 6;
    if ((t & 63) < 16){
#pragma unroll
        for (int uu=0; uu<UU; ++uu)
#pragma unroll
        for (int e=0; e<4; ++e){
            int c = j*4 + 64*uu + e;
            scr[0*4*O + wv*O + c] = s1[uu][e];
            scr[1*4*O + wv*O + c] = s2[uu][e];
            if (EXT){
                scr[2*4*O + wv*O + c] = mx[uu][e];
                scr[3*4*O + wv*O + c] = mn[uu][e];
            }
        }
    }
    __syncthreads();
    for (int c=t; c<O; c+=256){
        float S = ((scr[c] + scr[O+c]) + (scr[2*O+c] + scr[3*O+c]));
        float Q = ((scr[4*O+c] + scr[5*O+c]) + (scr[6*O+c] + scr[7*O+c]));
        pS[(size_t)blk*O + c] = S;
        pQ[(size_t)blk*O + c] = Q;
        if (EXT){
            constexpr int G  = 64/K;
            constexpr int WG = K/16;
#pragma unroll
            for (int g=0; g<G; ++g){
                float M1 = scr[2*4*O + (g*WG)*O + c];
                float M2 = scr[3*4*O + (g*WG)*O + c];
#pragma unroll
                for (int ww=1; ww<WG; ++ww){
                    M1 = fmaxf(M1, scr[2*4*O + (g*WG+ww)*O + c]);
                    M2 = fminf(M2, scr[3*4*O + (g*WG+ww)*O + c]);
                }
                int bs = m0/K + g;
                gmax[(size_t)bs*O + c] = M1;
                gmin[(size_t)bs*O + c] = M2;
            }
        }
    }
}

// ---------------- fused MLP phases ----------------
// PHASE 1: gather -> G1 -> stats1
// PHASE 2: gather -> G1 -> act1 -> G2 -> [store z2 bf16 if zbuf] -> stats2
// PHASE 3: full recompute -> act2 -> G3 -> stats3+extrema (fallback, no z2 buffer)
// PHASE 4: load z2 bf16 -> act2 -> G3 -> stats3+extrema (skips gather/G1/G2)
template<int PHASE, int K, int O1, int O2, int O3>
__global__ __launch_bounds__(256) void fused_mlp(
    const float* __restrict__ ptsT, const float* __restrict__ q, const int* __restrict__ gidx,
    const float* __restrict__ W1, const float* __restrict__ b1,
    const float* __restrict__ W2, const float* __restrict__ b2,
    const float* __restrict__ W3, const float* __restrict__ b3,
    const float* __restrict__ sc1, const float* __restrict__ sh1,
    const float* __restrict__ sc2, const float* __restrict__ sh2,
    float* __restrict__ pS, float* __restrict__ pQ,
    float* __restrict__ gmax, float* __restrict__ gmin,
    u16* __restrict__ zbuf)
{
    __shared__ float As[8192];   // 32 KB: [k][row], k up to 128
    __shared__ float Bs[4096];   // 16 KB: weight k-slabs [k][o] / stats scratch
    int t = threadIdx.x;
    int m0 = blockIdx.x * 64;
    int j = t & 15, i = t >> 4;

    if constexpr (PHASE != 4){
        // ---- gather A0 (64 rows x 64 ch) ----
        {
            int r = t >> 2, q4 = t & 3;
            int m = m0 + r;
            int idx = gidx[m];
            int bs = m / K;
            int b = bs >> 10;
            const float* base = ptsT + ((size_t)b*NN + idx)*64;
            float qx=0.f, qy=0.f, qz=0.f;
            if (q4 == 0){ qx = q[bs*3]; qy = q[bs*3+1]; qz = q[bs*3+2]; }
#pragma unroll
            for (int ii=0; ii<4; ++ii){
                int c0 = q4*16 + ii*4;
                float4 v = *(const float4*)(base + c0);
                if (q4==0 && ii==0){ v.x -= qx; v.y -= qy; v.z -= qz; }
                As[(c0+0)*64 + r] = v.x; As[(c0+1)*64 + r] = v.y;
                As[(c0+2)*64 + r] = v.z; As[(c0+3)*64 + r] = v.w;
            }
        }

        // ---- GEMM1 (C=64, O=O1), 32-k slabs ----
        constexpr int UU1 = O1/64;
        float acc1[4][UU1][4] = {};
        for (int k0=0; k0<64; k0+=32){
            __syncthreads();
#pragma unroll
            for (int it=0; it<O1/32; ++it){
                int slot = t + it*256;
                int o = slot >> 3, qq = slot & 7;
                float4 wv = *(const float4*)(W1 + o*64 + k0 + qq*4);
                Bs[(qq*4+0)*O1 + o] = wv.x; Bs[(qq*4+1)*O1 + o] = wv.y;
                Bs[(qq*4+2)*O1 + o] = wv.z; Bs[(qq*4+3)*O1 + o] = wv.w;
            }
            __syncthreads();
#pragma unroll 4
            for (int kk=0; kk<32; ++kk){
                float4 a4 = *(const float4*)&As[(k0+kk)*64 + i*4];
                fma_tile<UU1>(acc1, a4, &Bs[kk*O1], j*4);
            }
        }
        __syncthreads();

        if constexpr (PHASE == 1){
#pragma unroll
            for (int uu=0; uu<UU1; ++uu)
#pragma unroll
            for (int e=0; e<4; ++e){
                float bb = b1[j*4 + 64*uu + e];
#pragma unroll
                for (int rr=0; rr<4; ++rr) acc1[rr][uu][e] += bb;
            }
            stats_write<UU1,K,false>(acc1, t, m0, blockIdx.x, Bs, pS, pQ, gmax, gmin);
            return;
        }

        // ---- act1 -> As ----
#pragma unroll
        for (int uu=0; uu<UU1; ++uu)
#pragma unroll
        for (int e=0; e<4; ++e){
            int c = j*4 + 64*uu + e;
            float bb = b1[c], scv = sc1[c], shv = sh1[c];
#pragma unroll
            for (int rr=0; rr<4; ++rr)
                As[c*64 + i*4+rr] = fmaxf(0.f, (acc1[rr][uu][e]+bb)*scv + shv);
        }

        // ---- GEMM2 (C=O1, O=O2), 32-k slabs ----
        constexpr int UU2 = O2/64;
        float acc2[4][UU2][4] = {};
        for (int k0=0; k0<O1; k0+=32){
            __syncthreads();
#pragma unroll
            for (int it=0; it<O2/32; ++it){
                int slot = t + it*256;
                int o = slot >> 3, qq = slot & 7;
                float4 wv = *(const float4*)(W2 + o*O1 + k0 + qq*4);
                Bs[(qq*4+0)*O2 + o] = wv.x; Bs[(qq*4+1)*O2 + o] = wv.y;
                Bs[(qq*4+2)*O2 + o] = wv.z; Bs[(qq*4+3)*O2 + o] = wv.w;
            }
            __syncthreads();
#pragma unroll 4
            for (int kk=0; kk<32; ++kk){
                float4 a4 = *(const float4*)&As[(k0+kk)*64 + i*4];
                fma_tile<UU2>(acc2, a4, &Bs[kk*O2], j*4);
            }
        }
        __syncthreads();

        if constexpr (PHASE == 2){
#pragma unroll
            for (int uu=0; uu<UU2; ++uu)
#pragma unroll
            for (int e=0; e<4; ++e){
                float bb = b2[j*4+64*uu+e];
#pragma unroll
                for (int rr=0; rr<4; ++rr) acc2[rr][uu][e] += bb;
            }
            if (zbuf){   // materialize post-bias z2 as bf16 for PHASE 4
#pragma unroll
                for (int rr=0; rr<4; ++rr){
                    size_t row = (size_t)(m0 + i*4 + rr);
#pragma unroll
                    for (int uu=0; uu<UU2; ++uu){
                        ushort4 o4;
                        o4.x = f2bf(acc2[rr][uu][0]); o4.y = f2bf(acc2[rr][uu][1]);
                        o4.z = f2bf(acc2[rr][uu][2]); o4.w = f2bf(acc2[rr][uu][3]);
                        *(ushort4*)&zbuf[row*O2 + j*4 + 64*uu] = o4;
                    }
                }
            }
            stats_write<UU2,K,false>(acc2, t, m0, blockIdx.x, Bs, pS, pQ, gmax, gmin);
            return;
        }

        // ---- PHASE 3: act2 -> As ----
#pragma unroll
        for (int uu=0; uu<UU2; ++uu)
#pragma unroll
        for (int e=0; e<4; ++e){
            int c = j*4 + 64*uu + e;
            float bb = b2[c], scv = sc2[c], shv = sh2[c];
#pragma unroll
            for (int rr=0; rr<4; ++rr)
                As[c*64 + i*4+rr] = fmaxf(0.f, (acc2[rr][uu][e]+bb)*scv + shv);
        }
    } else {
        // ---- PHASE 4: load z2 (bf16, post-bias) -> act2 -> As ----
        constexpr int CQ = O2/4;
        constexpr int ITZ = 64*CQ/256;
#pragma unroll
        for (int it=0; it<ITZ; ++it){
            int slot = t + it*256;
            int r = slot / CQ, cq = slot % CQ;
            ushort4 zv = *(const ushort4*)&zbuf[((size_t)(m0+r))*O2 + cq*4];
            int c = cq*4;
            As[(c+0)*64+r] = fmaxf(0.f, bf2f(zv.x)*sc2[c+0] + sh2[c+0]);
            As[(c+1)*64+r] = fmaxf(0.f, bf2f(zv.y)*sc2[c+1] + sh2[c+1]);
            As[(c+2)*64+r] = fmaxf(0.f, bf2f(zv.z)*sc2[c+2] + sh2[c+2]);
            As[(c+3)*64+r] = fmaxf(0.f, bf2f(zv.w)*sc2[c+3] + sh2[c+3]);
        }
    }

    // ---- GEMM3 (C=O2, O=O3), KS3-k slabs (shared by PHASE 3 and 4) ----
    constexpr int UU3 = O3/64;
    constexpr int KS3 = 4096/O3;
    constexpr int QQ3 = KS3/4;
    float acc3[4][UU3][4] = {};
    for (int k0=0; k0<O2; k0+=KS3){
        __syncthreads();   // fences act2/z-load As-writes on first iter; prior Bs reads after
#pragma unroll
        for (int it=0; it<4; ++it){
            int slot = t + it*256;
            int o = slot / QQ3, qq = slot % QQ3;
            float4 wv = *(const float4*)(W3 + o*O2 + k0 + qq*4);
            Bs[(qq*4+0)*O3 + o] = wv.x; Bs[(qq*4+1)*O3 + o] = wv.y;
            Bs[(qq*4+2)*O3 + o] = wv.z; Bs[(qq*4+3)*O3 + o] = wv.w;
        }
        __syncthreads();
#pragma unroll 2
        for (int kk=0; kk<KS3; ++kk){
            float4 a4 = *(const float4*)&As[(k0+kk)*64 + i*4];
            fma_tile<UU3>(acc3, a4, &Bs[kk*O3], j*4);
        }
    }
    __syncthreads();

#pragma unroll
    for (int uu=0; uu<UU3; ++uu)
#pragma unroll
    for (int e=0; e<4; ++e){
        float bb = b3[j*4+64*uu+e];
#pragma unroll
        for (int rr=0; rr<4; ++rr) acc3[rr][uu][e] += bb;
    }
    stats_write<UU3,K,true>(acc3, t, m0, blockIdx.x, Bs, pS, pQ, gmax, gmin);
}

// ---------------- finalize BN stats (fp64 accumulation) ----------------
__global__ __launch_bounds__(256) void finalize_d_kernel(const float* __restrict__ pS, const float* __restrict__ pQ,
                                      const float* __restrict__ g, const float* __restrict__ bt,
                                      float* __restrict__ sc, float* __restrict__ sh, int nb, double invM){
    __shared__ double red[512];
    int c = blockIdx.x;
    int O = gridDim.x;
    int t = threadIdx.x;
    double S=0.0, Q=0.0;
    for (int v=t; v<nb; v+=256){ S += (double)pS[(size_t)v*O + c]; Q += (double)pQ[(size_t)v*O + c]; }
    red[t]=S; red[256+t]=Q;
    __syncthreads();
    for (int s=128; s>0; s>>=1){
        if (t<s){ red[t]+=red[t+s]; red[256+t]+=red[256+t+s]; }
        __syncthreads();
    }
    if (t==0){
        double mean = red[0]*invM;
        double var  = red[256]*invM - mean*mean;
        double scale = (double)g[c] / sqrt(var + 1e-5);
        sc[c] = (float)scale;
        sh[c] = (float)((double)bt[c] - mean*scale);
    }
}

// ---------------- BN+relu on pooled extrema -> output (fp32) ----------------
__global__ void final_out_kernel(const float* __restrict__ gmax, const float* __restrict__ gmin,
                                 const float* __restrict__ sc, const float* __restrict__ sh,
                                 float* __restrict__ outp, int O, int logO, int chbase){
    int gid = blockIdx.x*256 + threadIdx.x;   // over 8192*O
    int c  = gid & (O-1);
    int bs = gid >> logO;
    int b = bs >> 10, s = bs & 1023;
    float scale = sc[c];
    float v = (scale >= 0.f) ? gmax[gid] : gmin[gid];
    float r = fmaxf(0.f, scale*v + sh[c]);
    outp[((size_t)(b*640 + chbase + c))*SS + s] = r;
}

__global__ void ws_marker_kernel(float* outp, float wsval){ if (threadIdx.x==0) outp[0] = wsval; }

template<int K, int O1, int O2, int O3>
static void run_branch(const float* ptsT, const float* q, const int* gidx,
                       float* pS, float* pQ, float* gmax, float* gmin,
                       float* sc1, float* sh1, float* sc2, float* sh2, float* sc3, float* sh3,
                       u16* z2buf, bool use_z,
                       void* const* d_in, int wbase, float* np_out, int chbase, hipStream_t stream)
{
    const int M = BB*SS*K;
    const int nb = M/64;
    auto wp = [&](int jl, int which)->const float* { return (const float*)d_in[2 + (wbase+jl)*4 + which]; };
    const double invM = 1.0 / (double)M;
    u16* zb = use_z ? z2buf : (u16*)nullptr;

    fused_mlp<1,K,O1,O2,O3><<<nb,256,0,stream>>>(ptsT,q,gidx,
        wp(0,0),wp(0,1), wp(1,0),wp(1,1), wp(2,0),wp(2,1),
        sc1,sh1, sc2,sh2, pS,pQ, gmax,gmin, nullptr);
    finalize_d_kernel<<<O1,256,0,stream>>>(pS,pQ, wp(0,2), wp(0,3), sc1, sh1, nb, invM);

    fused_mlp<2,K,O1,O2,O3><<<nb,256,0,stream>>>(ptsT,q,gidx,
        wp(0,0),wp(0,1), wp(1,0),wp(1,1), wp(2,0),wp(2,1),
        sc1,sh1, sc2,sh2, pS,pQ, gmax,gmin, zb);
    finalize_d_kernel<<<O2,256,0,stream>>>(pS,pQ, wp(1,2), wp(1,3), sc2, sh2, nb, invM);

    if (use_z){
        fused_mlp<4,K,O1,O2,O3><<<nb,256,0,stream>>>(ptsT,q,gidx,
            wp(0,0),wp(0,1), wp(1,0),wp(1,1), wp(2,0),wp(2,1),
            sc1,sh1, sc2,sh2, pS,pQ, gmax,gmin, z2buf);
    } else {
        fused_mlp<3,K,O1,O2,O3><<<nb,256,0,stream>>>(ptsT,q,gidx,
            wp(0,0),wp(0,1), wp(1,0),wp(1,1), wp(2,0),wp(2,1),
            sc1,sh1, sc2,sh2, pS,pQ, gmax,gmin, nullptr);
    }
    finalize_d_kernel<<<O3,256,0,stream>>>(pS,pQ, wp(2,2), wp(2,3), sc3, sh3, nb, invM);

    final_out_kernel<<<(BB*SS*O3)/256,256,0,stream>>>(gmax,gmin, sc3,sh3, np_out, O3, (O3==256?8:7), chbase);
}

extern "C" void kernel_launch(void* const* d_in, const int* in_sizes, int n_in,
                              void* d_out, int out_size, void* d_ws, size_t ws_size,
                              hipStream_t stream)
{
    const float* xyz = (const float*)d_in[0];
    const float* pts = (const float*)d_in[1];
    float* outp = (float*)d_out;

    char* wsb = (char*)d_ws;
    size_t off = 0;
    auto alloc = [&](size_t bytes) -> void* {
        off = (off + 255) & ~(size_t)255;
        void* p = wsb + off;
        off += bytes;
        return p;
    };
    int*   fps_idx = (int*)  alloc((size_t)BB*SS*4);
    float* q       = (float*)alloc((size_t)BB*SS*3*4);
    int*   idx0    = (int*)  alloc((size_t)BB*SS*16*4);
    int*   idx1    = (int*)  alloc((size_t)BB*SS*32*4);
    int*   idx2    = (int*)  alloc((size_t)BB*SS*64*4);
    float* ptsT    = (float*)alloc((size_t)BB*NN*64*4);
    float* pS      = (float*)alloc((size_t)8192*256*4);
    float* pQ      = (float*)alloc((size_t)8192*256*4);
    float* gmax    = (float*)alloc((size_t)8192*256*4);
    float* gmin    = (float*)alloc((size_t)8192*256*4);
    float* sc1     = (float*)alloc(256*4);
    float* sh1     = (float*)alloc(256*4);
    float* sc2     = (float*)alloc(256*4);
    float* sh2     = (float*)alloc(256*4);
    float* sc3     = (float*)alloc(256*4);
    float* sh3     = (float*)alloc(256*4);

    if (off > ws_size){
        ws_marker_kernel<<<1,64,0,stream>>>(outp, (float)ws_size);
        return;
    }

    // optional z2 buffer (134 MB, reused across branches); activates PHASE-4 path if it fits
    u16* z2buf = (u16*)alloc((size_t)BB*SS*64*128*2);
    bool use_z = (off <= ws_size);

    build_ptsT_kernel<<<dim3(NN/64, BB), 256, 0, stream>>>(xyz, pts, ptsT);
    fps_kernel<<<BB, 512, 0, stream>>>(xyz, fps_idx);
    gather_q_kernel<<<32, 256, 0, stream>>>(xyz, fps_idx, q, outp);

    const float r2a = (float)(0.1*0.1);
    const float r2b = (float)(0.2*0.2);
    const float r2c = (float)(0.4*0.4);
    ballquery_kernel<<<2048, 256, 0, stream>>>(xyz, q, idx0, idx1, idx2, r2a, r2b, r2c);

    float* np_out = outp + (size_t)BB*3*SS;
    run_branch<16, 64, 64,128>(ptsT, q, idx0, pS,pQ, gmax,gmin, sc1,sh1,sc2,sh2,sc3,sh3, z2buf, use_z, d_in, 0, np_out,   0, stream);
    run_branch<32,128,128,256>(ptsT, q, idx1, pS,pQ, gmax,gmin, sc1,sh1,sc2,sh2,sc3,sh3, z2buf, use_z, d_in, 3, np_out, 128, stream);
    run_branch<64,128,128,256>(ptsT, q, idx2, pS,pQ, gmax,gmin, sc1,sh1,sc2,sh2,sc3,sh3, z2buf, use_z, d_in, 6, np_out, 384, stream);

    hipError_t e = hipGetLastError();
    if (e != hipSuccess){
        ws_marker_kernel<<<1,64,0,stream>>>(outp, 1000.0f + (float)(int)e);
    }
}

// Round 8
// 4469.762 us; speedup vs baseline: 1.1353x; 1.0207x over previous
//
#include <hip/hip_runtime.h>
#include <stdint.h>

#define BB 8
#define NN 16384
#define SS 1024

typedef unsigned short u16;
static __device__ __forceinline__ float bf2f(u16 u){
    union { uint32_t u; float f; } v; v.u = ((uint32_t)u) << 16; return v.f;
}
static __device__ __forceinline__ u16 f2bf(float f){
    union { float f; uint32_t u; } v; v.f = f;
    return (u16)((v.u + 0x7FFFu + ((v.u >> 16) & 1u)) >> 16);
}

// ---------------- FPS: one block per batch, 512 thr; asm barrier forces point residency in VGPRs ----------------
__global__ __launch_bounds__(512, 2) void fps_kernel(const float* __restrict__ xyz, int* __restrict__ fps_idx){
#pragma clang fp contract(off)
    int b = blockIdx.x;
    int t = threadIdx.x;
    const float* xb = xyz + (size_t)b*3*NN;
    float px[32], py[32], pz[32], dd[32];
#pragma unroll
    for (int j=0;j<32;++j){
        int n = t + j*512;
        px[j] = xb[n];
        py[j] = xb[NN+n];
        pz[j] = xb[2*NN+n];
        dd[j] = 1e10f;
    }
    // opaque redefinition: compiler cannot rematerialize the loads -> values stay in VGPRs
#pragma unroll
    for (int j=0;j<32;++j){
        asm volatile("" : "+v"(px[j]), "+v"(py[j]), "+v"(pz[j]));
    }
    __shared__ float rv[2][8];
    __shared__ int   rn[2][8];
    int lane = t & 63, wid = t >> 6;
    int far = 0;
    int* outp = fps_idx + b*SS;
    float cx = xb[0], cy = xb[NN], cz = xb[2*NN];
    for (int it=0; it<SS; ++it){
        if (t==0) outp[it] = far;
        float bestv = -1.0f; int bestn = 0x7fffffff;
#pragma unroll
        for (int j=0;j<32;++j){
            float dx = px[j]-cx, dy = py[j]-cy, dz = pz[j]-cz;
            float d = dx*dx + dy*dy;
            d = d + dz*dz;
            float dm = dd[j] < d ? dd[j] : d;   // np.minimum
            dd[j] = dm;
            if (dm > bestv){ bestv = dm; bestn = t + j*512; }  // strict > keeps lowest n in-thread
        }
#pragma unroll
        for (int off=32; off>0; off>>=1){
            float ov = __shfl_down(bestv, off);
            int   on = __shfl_down(bestn, off);
            if (ov > bestv || (ov == bestv && on < bestn)){ bestv = ov; bestn = on; }
        }
        int pb = it & 1;
        if (lane == 0){ rv[pb][wid] = bestv; rn[pb][wid] = bestn; }
        __syncthreads();
        float v2 = (lane < 8) ? rv[pb][lane] : -1.0f;
        int   n2 = (lane < 8) ? rn[pb][lane] : 0x7fffffff;
#pragma unroll
        for (int off=4; off>0; off>>=1){
            float ov = __shfl_down(v2, off);
            int   on = __shfl_down(n2, off);
            if (ov > v2 || (ov == v2 && on < n2)){ v2 = ov; n2 = on; }
        }
        far = __shfl(n2, 0);
        cx = xb[far]; cy = xb[NN+far]; cz = xb[2*NN+far];
    }
}

// ---------------- gather query coords + write new_xyz output (fp32) ----------------
__global__ void gather_q_kernel(const float* __restrict__ xyz, const int* __restrict__ fps_idx,
                                float* __restrict__ q, float* __restrict__ out_xyz){
    int i = blockIdx.x*blockDim.x + threadIdx.x;
    if (i >= BB*SS) return;
    int b = i >> 10, s = i & 1023;
    int idx = fps_idx[i];
    for (int c=0;c<3;++c){
        float v = xyz[((size_t)b*3+c)*NN + idx];
        q[i*3+c] = v;
        out_xyz[((size_t)b*3+c)*SS + s] = v;
    }
}

// ---------------- build ptsT[b][n][64] ----------------
__global__ __launch_bounds__(256) void build_ptsT_kernel(const float* __restrict__ xyz, const float* __restrict__ pts,
                                                         float* __restrict__ ptsT){
    __shared__ float tile[64][65];
    int b = blockIdx.y;
    int n0 = blockIdx.x * 64;
    int t = threadIdx.x;
    int ln = t & 63, cr = t >> 6;
    for (int c = cr; c < 64; c += 4){
        float v;
        if (c < 3) v = xyz[((size_t)b*3 + c)*NN + n0 + ln];
        else       v = pts[((size_t)b*61 + (c-3))*NN + n0 + ln];
        tile[ln][c] = v;
    }
    __syncthreads();
    int lc = t & 63, nr = t >> 6;
    for (int n = nr; n < 64; n += 4){
        ptsT[((size_t)b*NN + n0 + n)*64 + lc] = tile[n][lc];
    }
}

// ---------------- ball query ----------------
__global__ __launch_bounds__(256) void ballquery_kernel(const float* __restrict__ xyz, const float* __restrict__ q,
        int* __restrict__ idx0, int* __restrict__ idx1, int* __restrict__ idx2,
        float r2a, float r2b, float r2c){
#pragma clang fp contract(off)
    __shared__ int lds[4][112];
    int t = threadIdx.x;
    int w = t >> 6, lane = t & 63;
    int qi = blockIdx.x*4 + w;
    int b = qi >> 10;
    const float* xb = xyz + (size_t)b*3*NN;
    float qx = q[qi*3], qy = q[qi*3+1], qz = q[qi*3+2];
    float qn = qx*qx + qy*qy; qn = qn + qz*qz;
    int* l0 = lds[w];
    int* l1 = l0 + 16;
    int* l2 = l0 + 48;
    l0[lane] = 0;
    if (lane < 48) l0[64+lane] = 0;
    int c0=0, c1=0, c2=0;
    uint64_t below = (1ull << lane) - 1ull;
    for (int ch=0; ch<256; ++ch){
        int n = ch*64 + lane;
        float x = xb[n], y = xb[NN+n], z = xb[2*NN+n];
        float dn = x*x + y*y; dn = dn + z*z;
        float dot = qx*x + qy*y; dot = dot + qz*z;
        float d = -2.0f*dot + qn;
        d = d + dn;
        bool o0 = d <= r2a, o1 = d <= r2b, o2 = d <= r2c;
        uint64_t m0 = __ballot(o0), m1 = __ballot(o1), m2 = __ballot(o2);
        if (c0 < 16){
            int p = c0 + (int)__popcll(m0 & below);
            if (o0 && p < 16) l0[p] = n;
            c0 += (int)__popcll(m0); if (c0 > 16) c0 = 16;
        }
        if (c1 < 32){
            int p = c1 + (int)__popcll(m1 & below);
            if (o1 && p < 32) l1[p] = n;
            c1 += (int)__popcll(m1); if (c1 > 32) c1 = 32;
        }
        if (c2 < 64){
            int p = c2 + (int)__popcll(m2 & below);
            if (o2 && p < 64) l2[p] = n;
            c2 += (int)__popcll(m2); if (c2 > 64) c2 = 64;
        }
        if (c0>=16 && c1>=32 && c2>=64) break;
    }
    __syncthreads();
    int f0 = l0[0], f1 = l1[0], f2 = l2[0];
    if (lane >= c0 && lane < 16) l0[lane] = f0;
    if (lane >= c1 && lane < 32) l1[lane] = f1;
    if (lane >= c2)              l2[lane] = f2;
    __syncthreads();
    if (lane < 16) idx0[(size_t)qi*16 + lane] = l0[lane];
    if (lane < 32) idx1[(size_t)qi*32 + lane] = l1[lane];
    idx2[(size_t)qi*64 + lane] = l2[lane];
}

// ---------------- MAC helper ----------------
template<int UU>
__device__ __forceinline__ void fma_tile(float (&acc)[4][UU][4], float4 a4, const float* bsrow, int jbase){
#pragma unroll
    for (int uu=0; uu<UU; ++uu){
        float4 b4 = *(const float4*)(bsrow + jbase + 64*uu);
        acc[0][uu][0]+=a4.x*b4.x; acc[0][uu][1]+=a4.x*b4.y; acc[0][uu][2]+=a4.x*b4.z; acc[0][uu][3]+=a4.x*b4.w;
        acc[1][uu][0]+=a4.y*b4.x; acc[1][uu][1]+=a4.y*b4.y; acc[1][uu][2]+=a4.y*b4.z; acc[1][uu][3]+=a4.y*b4.w;
        acc[2][uu][0]+=a4.z*b4.x; acc[2][uu][1]+=a4.z*b4.y; acc[2][uu][2]+=a4.z*b4.z; acc[2][uu][3]+=a4.z*b4.w;
        acc[3][uu][0]+=a4.w*b4.x; acc[3][uu][1]+=a4.w*b4.y; acc[3][uu][2]+=a4.w*b4.z; acc[3][uu][3]+=a4.w*b4.w;
    }
}

// ---------------- unified GEMM: As [k][row] x W[OO][CC] staged in k-slabs -> acc ----------------
template<int CC, int OO>
__device__ __forceinline__ void gemm_slab(const float* __restrict__ W, int t, int i, int j,
                                          float* As, float* Bs, float (&acc)[4][OO/64][4]){
    constexpr int KS = (4096/OO) < 32 ? (4096/OO) : 32;
    constexpr int QQ = KS/4;
    constexpr int NSLOT = KS*OO/4;
    for (int k0=0; k0<CC; k0+=KS){
        __syncthreads();
#pragma unroll
        for (int it=0; it<NSLOT/256; ++it){
            int slot = t + it*256;
            int o = slot / QQ, qq = slot % QQ;
            float4 wv = *(const float4*)(W + o*CC + k0 + qq*4);
            Bs[(qq*4+0)*OO + o] = wv.x; Bs[(qq*4+1)*OO + o] = wv.y;
            Bs[(qq*4+2)*OO + o] = wv.z; Bs[(qq*4+3)*OO + o] = wv.w;
        }
        __syncthreads();
#pragma unroll 4
        for (int kk=0; kk<KS; ++kk){
            float4 a4 = *(const float4*)&As[(k0+kk)*64 + i*4];
            fma_tile<OO/64>(acc, a4, &Bs[kk*OO], j*4);
        }
    }
    __syncthreads();
}

template<int UU>
__device__ __forceinline__ void bias_add(float (&acc)[4][UU][4], const float* __restrict__ bsrc, int j){
#pragma unroll
    for (int uu=0; uu<UU; ++uu)
#pragma unroll
    for (int e=0; e<4; ++e){
        float bb = bsrc[j*4 + 64*uu + e];
#pragma unroll
        for (int rr=0; rr<4; ++rr) acc[rr][uu][e] += bb;
    }
}

// act(acc) -> As [c][row]
template<int UU>
__device__ __forceinline__ void act_to_As(float (&acc)[4][UU][4], const float* __restrict__ bsrc,
                                          const float* __restrict__ sc, const float* __restrict__ sh,
                                          int i, int j, float* As){
#pragma unroll
    for (int uu=0; uu<UU; ++uu)
#pragma unroll
    for (int e=0; e<4; ++e){
        int c = j*4 + 64*uu + e;
        float bb = bsrc[c], scv = sc[c], shv = sh[c];
#pragma unroll
        for (int rr=0; rr<4; ++rr)
            As[c*64 + i*4+rr] = fmaxf(0.f, (acc[rr][uu][e]+bb)*scv + shv);
    }
}

// store post-bias acc as bf16 z[m][OO]
template<int UU>
__device__ __forceinline__ void zstore(float (&acc)[4][UU][4], u16* __restrict__ zbuf, int m0, int i, int j){
    constexpr int OO = UU*64;
#pragma unroll
    for (int rr=0; rr<4; ++rr){
        size_t row = (size_t)(m0 + i*4 + rr);
#pragma unroll
        for (int uu=0; uu<UU; ++uu){
            ushort4 o4;
            o4.x = f2bf(acc[rr][uu][0]); o4.y = f2bf(acc[rr][uu][1]);
            o4.z = f2bf(acc[rr][uu][2]); o4.w = f2bf(acc[rr][uu][3]);
            *(ushort4*)&zbuf[row*OO + j*4 + 64*uu] = o4;
        }
    }
}

// load bf16 z[m][OO], apply scale/shift+relu -> As [c][row]
template<int OO>
__device__ __forceinline__ void zload_to_As(const u16* __restrict__ zbuf, int m0,
                                            const float* __restrict__ sc, const float* __restrict__ sh,
                                            int t, float* As){
    constexpr int CQ = OO/4;
    constexpr int ITZ = 64*CQ/256;
#pragma unroll
    for (int it=0; it<ITZ; ++it){
        int slot = t + it*256;
        int r = slot / CQ, cq = slot % CQ;
        ushort4 zv = *(const ushort4*)&zbuf[((size_t)(m0+r))*OO + cq*4];
        int c = cq*4;
        As[(c+0)*64+r] = fmaxf(0.f, bf2f(zv.x)*sc[c+0] + sh[c+0]);
        As[(c+1)*64+r] = fmaxf(0.f, bf2f(zv.y)*sc[c+1] + sh[c+1]);
        As[(c+2)*64+r] = fmaxf(0.f, bf2f(zv.z)*sc[c+2] + sh[c+2]);
        As[(c+3)*64+r] = fmaxf(0.f, bf2f(zv.w)*sc[c+3] + sh[c+3]);
    }
}

// ---------------- stats / extrema epilogue ----------------
template<int UU, int K, bool EXT>
__device__ __forceinline__ void stats_write(float (&z)[4][UU][4], int t, int m0, int blk,
    float* scr, float* __restrict__ pS, float* __restrict__ pQ,
    float* __restrict__ gmax, float* __restrict__ gmin)
{
    constexpr int O = UU*64;
    int j = t & 15;
    float s1[UU][4], s2[UU][4], mx[UU][4], mn[UU][4];
#pragma unroll
    for (int uu=0; uu<UU; ++uu)
#pragma unroll
    for (int e=0; e<4; ++e){
        float v0=z[0][uu][e], v1=z[1][uu][e], v2=z[2][uu][e], v3=z[3][uu][e];
        s1[uu][e]=(v0+v1)+(v2+v3);
        s2[uu][e]=(v0*v0+v1*v1)+(v2*v2+v3*v3);
        if (EXT){
            mx[uu][e]=fmaxf(fmaxf(v0,v1),fmaxf(v2,v3));
            mn[uu][e]=fminf(fminf(v0,v1),fminf(v2,v3));
        }
    }
#pragma unroll
    for (int uu=0; uu<UU; ++uu)
#pragma unroll
    for (int e=0; e<4; ++e){
        s1[uu][e] += __shfl_xor(s1[uu][e],16); s1[uu][e] += __shfl_xor(s1[uu][e],32);
        s2[uu][e] += __shfl_xor(s2[uu][e],16); s2[uu][e] += __shfl_xor(s2[uu][e],32);
        if (EXT){
            mx[uu][e] = fmaxf(mx[uu][e], __shfl_xor(mx[uu][e],16)); mx[uu][e] = fmaxf(mx[uu][e], __shfl_xor(mx[uu][e],32));
            mn[uu][e] = fminf(mn[uu][e], __shfl_xor(mn[uu][e],16)); mn[uu][e] = fminf(mn[uu][e], __shfl_xor(mn[uu][e],32));
        }
    }
    int wv = t >> 6;
    if ((t & 63) < 16){
#pragma unroll
        for (int uu=0; uu<UU; ++uu)
#pragma unroll
        for (int e=0; e<4; ++e){
            int c = j*4 + 64*uu + e;
            scr[0*4*O + wv*O + c] = s1[uu][e];
            scr[1*4*O + wv*O + c] = s2[uu][e];
            if (EXT){
                scr[2*4*O + wv*O + c] = mx[uu][e];
                scr[3*4*O + wv*O + c] = mn[uu][e];
            }
        }
    }
    __syncthreads();
    for (int c=t; c<O; c+=256){
        float S = ((scr[c] + scr[O+c]) + (scr[2*O+c] + scr[3*O+c]));
        float Q = ((scr[4*O+c] + scr[5*O+c]) + (scr[6*O+c] + scr[7*O+c]));
        pS[(size_t)blk*O + c] = S;
        pQ[(size_t)blk*O + c] = Q;
        if (EXT){
            constexpr int G  = 64/K;
            constexpr int WG = K/16;
#pragma unroll
            for (int g=0; g<G; ++g){
                float M1 = scr[2*4*O + (g*WG)*O + c];
                float M2 = scr[3*4*O + (g*WG)*O + c];
#pragma unroll
                for (int ww=1; ww<WG; ++ww){
                    M1 = fmaxf(M1, scr[2*4*O + (g*WG+ww)*O + c]);
                    M2 = fminf(M2, scr[3*4*O + (g*WG+ww)*O + c]);
                }
                int bs = m0/K + g;
                gmax[(size_t)bs*O + c] = M1;
                gmin[(size_t)bs*O + c] = M2;
            }
        }
    }
}

// gather grouped input -> As [c][row]
template<int K>
__device__ __forceinline__ void gather_A0(const float* __restrict__ ptsT, const float* __restrict__ q,
                                          const int* __restrict__ gidx, int m0, int t, float* As){
    int r = t >> 2, q4 = t & 3;
    int m = m0 + r;
    int idx = gidx[m];
    int bs = m / K;
    int b = bs >> 10;
    const float* base = ptsT + ((size_t)b*NN + idx)*64;
    float qx=0.f, qy=0.f, qz=0.f;
    if (q4 == 0){ qx = q[bs*3]; qy = q[bs*3+1]; qz = q[bs*3+2]; }
#pragma unroll
    for (int ii=0; ii<4; ++ii){
        int c0 = q4*16 + ii*4;
        float4 v = *(const float4*)(base + c0);
        if (q4==0 && ii==0){ v.x -= qx; v.y -= qy; v.z -= qz; }
        As[(c0+0)*64 + r] = v.x; As[(c0+1)*64 + r] = v.y;
        As[(c0+2)*64 + r] = v.z; As[(c0+3)*64 + r] = v.w;
    }
}

// ---------------- fused MLP phases ----------------
// PHASE 1: gather -> G1 -> [store z1 bf16] -> stats1
// PHASE 2: [load z1 | recompute] -> act1 -> G2 -> [store z2 bf16] -> stats2
// PHASE 3: full recompute -> G3 -> stats3+extrema (fallback when no z buffer)
// PHASE 4: load z2 -> act2 -> G3 -> stats3+extrema
template<int PHASE, int K, int O1, int O2, int O3>
__global__ __launch_bounds__(256) void fused_mlp(
    const float* __restrict__ ptsT, const float* __restrict__ q, const int* __restrict__ gidx,
    const float* __restrict__ W1, const float* __restrict__ b1,
    const float* __restrict__ W2, const float* __restrict__ b2,
    const float* __restrict__ W3, const float* __restrict__ b3,
    const float* __restrict__ sc1, const float* __restrict__ sh1,
    const float* __restrict__ sc2, const float* __restrict__ sh2,
    float* __restrict__ pS, float* __restrict__ pQ,
    float* __restrict__ gmax, float* __restrict__ gmin,
    u16* __restrict__ zbuf)
{
    __shared__ float As[8192];   // 32 KB
    __shared__ float Bs[4096];   // 16 KB
    int t = threadIdx.x;
    int m0 = blockIdx.x * 64;
    int j = t & 15, i = t >> 4;

    if constexpr (PHASE == 1){
        gather_A0<K>(ptsT, q, gidx, m0, t, As);
        float acc1[4][O1/64][4] = {};
        gemm_slab<64,O1>(W1, t, i, j, As, Bs, acc1);
        bias_add<O1/64>(acc1, b1, j);
        if (zbuf) zstore<O1/64>(acc1, zbuf, m0, i, j);
        stats_write<O1/64,K,false>(acc1, t, m0, blockIdx.x, Bs, pS, pQ, gmax, gmin);
        return;
    }

    if constexpr (PHASE == 2){
        if (zbuf){
            zload_to_As<O1>(zbuf, m0, sc1, sh1, t, As);
        } else {
            gather_A0<K>(ptsT, q, gidx, m0, t, As);
            float acc1[4][O1/64][4] = {};
            gemm_slab<64,O1>(W1, t, i, j, As, Bs, acc1);
            act_to_As<O1/64>(acc1, b1, sc1, sh1, i, j, As);
        }
        float acc2[4][O2/64][4] = {};
        gemm_slab<O1,O2>(W2, t, i, j, As, Bs, acc2);
        bias_add<O2/64>(acc2, b2, j);
        if (zbuf) zstore<O2/64>(acc2, zbuf, m0, i, j);   // overwrites z1 rows (block-local, safe)
        stats_write<O2/64,K,false>(acc2, t, m0, blockIdx.x, Bs, pS, pQ, gmax, gmin);
        return;
    }

    if constexpr (PHASE == 3){
        gather_A0<K>(ptsT, q, gidx, m0, t, As);
        float acc1[4][O1/64][4] = {};
        gemm_slab<64,O1>(W1, t, i, j, As, Bs, acc1);
        act_to_As<O1/64>(acc1, b1, sc1, sh1, i, j, As);
        float acc2[4][O2/64][4] = {};
        gemm_slab<O1,O2>(W2, t, i, j, As, Bs, acc2);
        act_to_As<O2/64>(acc2, b2, sc2, sh2, i, j, As);
    } else {
        // PHASE 4
        zload_to_As<O2>(zbuf, m0, sc2, sh2, t, As);
    }

    float acc3[4][O3/64][4] = {};
    gemm_slab<O2,O3>(W3, t, i, j, As, Bs, acc3);
    bias_add<O3/64>(acc3, b3, j);
    stats_write<O3/64,K,true>(acc3, t, m0, blockIdx.x, Bs, pS, pQ, gmax, gmin);
}

// ---------------- finalize BN stats (fp64 accumulation) ----------------
__global__ __launch_bounds__(256) void finalize_d_kernel(const float* __restrict__ pS, const float* __restrict__ pQ,
                                      const float* __restrict__ g, const float* __restrict__ bt,
                                      float* __restrict__ sc, float* __restrict__ sh, int nb, double invM){
    __shared__ double red[512];
    int c = blockIdx.x;
    int O = gridDim.x;
    int t = threadIdx.x;
    double S=0.0, Q=0.0;
    for (int v=t; v<nb; v+=256){ S += (double)pS[(size_t)v*O + c]; Q += (double)pQ[(size_t)v*O + c]; }
    red[t]=S; red[256+t]=Q;
    __syncthreads();
    for (int s=128; s>0; s>>=1){
        if (t<s){ red[t]+=red[t+s]; red[256+t]+=red[256+t+s]; }
        __syncthreads();
    }
    if (t==0){
        double mean = red[0]*invM;
        double var  = red[256]*invM - mean*mean;
        double scale = (double)g[c] / sqrt(var + 1e-5);
        sc[c] = (float)scale;
        sh[c] = (float)((double)bt[c] - mean*scale);
    }
}

// ---------------- BN+relu on pooled extrema -> output (fp32) ----------------
__global__ void final_out_kernel(const float* __restrict__ gmax, const float* __restrict__ gmin,
                                 const float* __restrict__ sc, const float* __restrict__ sh,
                                 float* __restrict__ outp, int O, int logO, int chbase){
    int gid = blockIdx.x*256 + threadIdx.x;
    int c  = gid & (O-1);
    int bs = gid >> logO;
    int b = bs >> 10, s = bs & 1023;
    float scale = sc[c];
    float v = (scale >= 0.f) ? gmax[gid] : gmin[gid];
    float r = fmaxf(0.f, scale*v + sh[c]);
    outp[((size_t)(b*640 + chbase + c))*SS + s] = r;
}

__global__ void ws_marker_kernel(float* outp, float wsval){ if (threadIdx.x==0) outp[0] = wsval; }

template<int K, int O1, int O2, int O3>
static void run_branch(const float* ptsT, const float* q, const int* gidx,
                       float* pS, float* pQ, float* gmax, float* gmin,
                       float* sc1, float* sh1, float* sc2, float* sh2, float* sc3, float* sh3,
                       u16* z2buf, bool use_z,
                       void* const* d_in, int wbase, float* np_out, int chbase, hipStream_t stream)
{
    const int M = BB*SS*K;
    const int nb = M/64;
    auto wp = [&](int jl, int which)->const float* { return (const float*)d_in[2 + (wbase+jl)*4 + which]; };
    const double invM = 1.0 / (double)M;
    u16* zb = use_z ? z2buf : (u16*)nullptr;

    fused_mlp<1,K,O1,O2,O3><<<nb,256,0,stream>>>(ptsT,q,gidx,
        wp(0,0),wp(0,1), wp(1,0),wp(1,1), wp(2,0),wp(2,1),
        sc1,sh1, sc2,sh2, pS,pQ, gmax,gmin, zb);
    finalize_d_kernel<<<O1,256,0,stream>>>(pS,pQ, wp(0,2), wp(0,3), sc1, sh1, nb, invM);

    fused_mlp<2,K,O1,O2,O3><<<nb,256,0,stream>>>(ptsT,q,gidx,
        wp(0,0),wp(0,1), wp(1,0),wp(1,1), wp(2,0),wp(2,1),
        sc1,sh1, sc2,sh2, pS,pQ, gmax,gmin, zb);
    finalize_d_kernel<<<O2,256,0,stream>>>(pS,pQ, wp(1,2), wp(1,3), sc2, sh2, nb, invM);

    if (use_z){
        fused_mlp<4,K,O1,O2,O3><<<nb,256,0,stream>>>(ptsT,q,gidx,
            wp(0,0),wp(0,1), wp(1,0),wp(1,1), wp(2,0),wp(2,1),
            sc1,sh1, sc2,sh2, pS,pQ, gmax,gmin, z2buf);
    } else {
        fused_mlp<3,K,O1,O2,O3><<<nb,256,0,stream>>>(ptsT,q,gidx,
            wp(0,0),wp(0,1), wp(1,0),wp(1,1), wp(2,0),wp(2,1),
            sc1,sh1, sc2,sh2, pS,pQ, gmax,gmin, nullptr);
    }
    finalize_d_kernel<<<O3,256,0,stream>>>(pS,pQ, wp(2,2), wp(2,3), sc3, sh3, nb, invM);

    final_out_kernel<<<(BB*SS*O3)/256,256,0,stream>>>(gmax,gmin, sc3,sh3, np_out, O3, (O3==256?8:7), chbase);
}

extern "C" void kernel_launch(void* const* d_in, const int* in_sizes, int n_in,
                              void* d_out, int out_size, void* d_ws, size_t ws_size,
                              hipStream_t stream)
{
    const float* xyz = (const float*)d_in[0];
    const float* pts = (const float*)d_in[1];
    float* outp = (float*)d_out;

    char* wsb = (char*)d_ws;
    size_t off = 0;
    auto alloc = [&](size_t bytes) -> void* {
        off = (off + 255) & ~(size_t)255;
        void* p = wsb + off;
        off += bytes;
        return p;
    };
    int*   fps_idx = (int*)  alloc((size_t)BB*SS*4);
    float* q       = (float*)alloc((size_t)BB*SS*3*4);
    int*   idx0    = (int*)  alloc((size_t)BB*SS*16*4);
    int*   idx1    = (int*)  alloc((size_t)BB*SS*32*4);
    int*   idx2    = (int*)  alloc((size_t)BB*SS*64*4);
    float* ptsT    = (float*)alloc((size_t)BB*NN*64*4);
    float* pS      = (float*)alloc((size_t)8192*256*4);
    float* pQ      = (float*)alloc((size_t)8192*256*4);
    float* gmax    = (float*)alloc((size_t)8192*256*4);
    float* gmin    = (float*)alloc((size_t)8192*256*4);
    float* sc1     = (float*)alloc(256*4);
    float* sh1     = (float*)alloc(256*4);
    float* sc2     = (float*)alloc(256*4);
    float* sh2     = (float*)alloc(256*4);
    float* sc3     = (float*)alloc(256*4);
    float* sh3     = (float*)alloc(256*4);

    if (off > ws_size){
        ws_marker_kernel<<<1,64,0,stream>>>(outp, (float)ws_size);
        return;
    }

    // z buffer (134 MB, holds z1 then z2 in-place, reused across branches)
    u16* z2buf = (u16*)alloc((size_t)BB*SS*64*128*2);
    bool use_z = (off <= ws_size);

    build_ptsT_kernel<<<dim3(NN/64, BB), 256, 0, stream>>>(xyz, pts, ptsT);
    fps_kernel<<<BB, 512, 0, stream>>>(xyz, fps_idx);
    gather_q_kernel<<<32, 256, 0, stream>>>(xyz, fps_idx, q, outp);

    const float r2a = (float)(0.1*0.1);
    const float r2b = (float)(0.2*0.2);
    const float r2c = (float)(0.4*0.4);
    ballquery_kernel<<<2048, 256, 0, stream>>>(xyz, q, idx0, idx1, idx2, r2a, r2b, r2c);

    float* np_out = outp + (size_t)BB*3*SS;
    run_branch<16, 64, 64,128>(ptsT, q, idx0, pS,pQ, gmax,gmin, sc1,sh1,sc2,sh2,sc3,sh3, z2buf, use_z, d_in, 0, np_out,   0, stream);
    run_branch<32,128,128,256>(ptsT, q, idx1, pS,pQ, gmax,gmin, sc1,sh1,sc2,sh2,sc3,sh3, z2buf, use_z, d_in, 3, np_out, 128, stream);
    run_branch<64,128,128,256>(ptsT, q, idx2, pS,pQ, gmax,gmin, sc1,sh1,sc2,sh2,sc3,sh3, z2buf, use_z, d_in, 6, np_out, 384, stream);

    hipError_t e = hipGetLastError();
    if (e != hipSuccess){
        ws_marker_kernel<<<1,64,0,stream>>>(outp, 1000.0f + (float)(int)e);
    }
}

// Round 9
// 4467.556 us; speedup vs baseline: 1.1359x; 1.0005x over previous
//
#include <hip/hip_runtime.h>
#include <stdint.h>

#define BB 8
#define NN 16384
#define SS 1024

typedef unsigned short u16;
static __device__ __forceinline__ float bf2f(u16 u){
    union { uint32_t u; float f; } v; v.u = ((uint32_t)u) << 16; return v.f;
}
static __device__ __forceinline__ u16 f2bf(float f){
    union { float f; uint32_t u; } v; v.f = f;
    return (u16)((v.u + 0x7FFFu + ((v.u >> 16) & 1u)) >> 16);
}

// ---------------- FPS: one block per batch, 512 thr ----------------
// amdgpu_waves_per_eu(1,2): occupancy floor 1 wave/EU -> VGPR cap = arch max, so the
// 96 coord + 32 dd floats stay resident (R6/R8: cap 128 -> forced spill, VGPR=84, ~2250us)
__global__ __launch_bounds__(512) __attribute__((amdgpu_waves_per_eu(1, 2)))
void fps_kernel(const float* __restrict__ xyz, int* __restrict__ fps_idx){
#pragma clang fp contract(off)
    int b = blockIdx.x;
    int t = threadIdx.x;
    const float* xb = xyz + (size_t)b*3*NN;
    float px[32], py[32], pz[32], dd[32];
#pragma unroll
    for (int j=0;j<32;++j){
        int n = t + j*512;
        px[j] = xb[n];
        py[j] = xb[NN+n];
        pz[j] = xb[2*NN+n];
        dd[j] = 1e10f;
    }
    // opaque redefinition: compiler cannot rematerialize the loads
#pragma unroll
    for (int j=0;j<32;++j){
        asm volatile("" : "+v"(px[j]), "+v"(py[j]), "+v"(pz[j]));
    }
    __shared__ float rv[2][8];
    __shared__ int   rn[2][8];
    int lane = t & 63, wid = t >> 6;
    int far = 0;
    int* outp = fps_idx + b*SS;
    float cx = xb[0], cy = xb[NN], cz = xb[2*NN];
    for (int it=0; it<SS; ++it){
        if (t==0) outp[it] = far;
        float bestv = -1.0f; int bestn = 0x7fffffff;
#pragma unroll
        for (int j=0;j<32;++j){
            float dx = px[j]-cx, dy = py[j]-cy, dz = pz[j]-cz;
            float d = dx*dx + dy*dy;
            d = d + dz*dz;
            float dm = dd[j] < d ? dd[j] : d;   // np.minimum
            dd[j] = dm;
            if (dm > bestv){ bestv = dm; bestn = t + j*512; }  // strict > keeps lowest n in-thread
        }
#pragma unroll
        for (int off=32; off>0; off>>=1){
            float ov = __shfl_down(bestv, off);
            int   on = __shfl_down(bestn, off);
            if (ov > bestv || (ov == bestv && on < bestn)){ bestv = ov; bestn = on; }
        }
        int pb = it & 1;
        if (lane == 0){ rv[pb][wid] = bestv; rn[pb][wid] = bestn; }
        __syncthreads();
        float v2 = (lane < 8) ? rv[pb][lane] : -1.0f;
        int   n2 = (lane < 8) ? rn[pb][lane] : 0x7fffffff;
#pragma unroll
        for (int off=4; off>0; off>>=1){
            float ov = __shfl_down(v2, off);
            int   on = __shfl_down(n2, off);
            if (ov > v2 || (ov == v2 && on < n2)){ v2 = ov; n2 = on; }
        }
        far = __shfl(n2, 0);
        cx = xb[far]; cy = xb[NN+far]; cz = xb[2*NN+far];
    }
}

// ---------------- gather query coords + write new_xyz output (fp32) ----------------
__global__ void gather_q_kernel(const float* __restrict__ xyz, const int* __restrict__ fps_idx,
                                float* __restrict__ q, float* __restrict__ out_xyz){
    int i = blockIdx.x*blockDim.x + threadIdx.x;
    if (i >= BB*SS) return;
    int b = i >> 10, s = i & 1023;
    int idx = fps_idx[i];
    for (int c=0;c<3;++c){
        float v = xyz[((size_t)b*3+c)*NN + idx];
        q[i*3+c] = v;
        out_xyz[((size_t)b*3+c)*SS + s] = v;
    }
}

// ---------------- build ptsT[b][n][64] ----------------
__global__ __launch_bounds__(256) void build_ptsT_kernel(const float* __restrict__ xyz, const float* __restrict__ pts,
                                                         float* __restrict__ ptsT){
    __shared__ float tile[64][65];
    int b = blockIdx.y;
    int n0 = blockIdx.x * 64;
    int t = threadIdx.x;
    int ln = t & 63, cr = t >> 6;
    for (int c = cr; c < 64; c += 4){
        float v;
        if (c < 3) v = xyz[((size_t)b*3 + c)*NN + n0 + ln];
        else       v = pts[((size_t)b*61 + (c-3))*NN + n0 + ln];
        tile[ln][c] = v;
    }
    __syncthreads();
    int lc = t & 63, nr = t >> 6;
    for (int n = nr; n < 64; n += 4){
        ptsT[((size_t)b*NN + n0 + n)*64 + lc] = tile[n][lc];
    }
}

// ---------------- ball query ----------------
__global__ __launch_bounds__(256) void ballquery_kernel(const float* __restrict__ xyz, const float* __restrict__ q,
        int* __restrict__ idx0, int* __restrict__ idx1, int* __restrict__ idx2,
        float r2a, float r2b, float r2c){
#pragma clang fp contract(off)
    __shared__ int lds[4][112];
    int t = threadIdx.x;
    int w = t >> 6, lane = t & 63;
    int qi = blockIdx.x*4 + w;
    int b = qi >> 10;
    const float* xb = xyz + (size_t)b*3*NN;
    float qx = q[qi*3], qy = q[qi*3+1], qz = q[qi*3+2];
    float qn = qx*qx + qy*qy; qn = qn + qz*qz;
    int* l0 = lds[w];
    int* l1 = l0 + 16;
    int* l2 = l0 + 48;
    l0[lane] = 0;
    if (lane < 48) l0[64+lane] = 0;
    int c0=0, c1=0, c2=0;
    uint64_t below = (1ull << lane) - 1ull;
    for (int ch=0; ch<256; ++ch){
        int n = ch*64 + lane;
        float x = xb[n], y = xb[NN+n], z = xb[2*NN+n];
        float dn = x*x + y*y; dn = dn + z*z;
        float dot = qx*x + qy*y; dot = dot + qz*z;
        float d = -2.0f*dot + qn;
        d = d + dn;
        bool o0 = d <= r2a, o1 = d <= r2b, o2 = d <= r2c;
        uint64_t m0 = __ballot(o0), m1 = __ballot(o1), m2 = __ballot(o2);
        if (c0 < 16){
            int p = c0 + (int)__popcll(m0 & below);
            if (o0 && p < 16) l0[p] = n;
            c0 += (int)__popcll(m0); if (c0 > 16) c0 = 16;
        }
        if (c1 < 32){
            int p = c1 + (int)__popcll(m1 & below);
            if (o1 && p < 32) l1[p] = n;
            c1 += (int)__popcll(m1); if (c1 > 32) c1 = 32;
        }
        if (c2 < 64){
            int p = c2 + (int)__popcll(m2 & below);
            if (o2 && p < 64) l2[p] = n;
            c2 += (int)__popcll(m2); if (c2 > 64) c2 = 64;
        }
        if (c0>=16 && c1>=32 && c2>=64) break;
    }
    __syncthreads();
    int f0 = l0[0], f1 = l1[0], f2 = l2[0];
    if (lane >= c0 && lane < 16) l0[lane] = f0;
    if (lane >= c1 && lane < 32) l1[lane] = f1;
    if (lane >= c2)              l2[lane] = f2;
    __syncthreads();
    if (lane < 16) idx0[(size_t)qi*16 + lane] = l0[lane];
    if (lane < 32) idx1[(size_t)qi*32 + lane] = l1[lane];
    idx2[(size_t)qi*64 + lane] = l2[lane];
}

// ---------------- MAC helper ----------------
template<int UU>
__device__ __forceinline__ void fma_tile(float (&acc)[4][UU][4], float4 a4, const float* bsrow, int jbase){
#pragma unroll
    for (int uu=0; uu<UU; ++uu){
        float4 b4 = *(const float4*)(bsrow + jbase + 64*uu);
        acc[0][uu][0]+=a4.x*b4.x; acc[0][uu][1]+=a4.x*b4.y; acc[0][uu][2]+=a4.x*b4.z; acc[0][uu][3]+=a4.x*b4.w;
        acc[1][uu][0]+=a4.y*b4.x; acc[1][uu][1]+=a4.y*b4.y; acc[1][uu][2]+=a4.y*b4.z; acc[1][uu][3]+=a4.y*b4.w;
        acc[2][uu][0]+=a4.z*b4.x; acc[2][uu][1]+=a4.z*b4.y; acc[2][uu][2]+=a4.z*b4.z; acc[2][uu][3]+=a4.z*b4.w;
        acc[3][uu][0]+=a4.w*b4.x; acc[3][uu][1]+=a4.w*b4.y; acc[3][uu][2]+=a4.w*b4.z; acc[3][uu][3]+=a4.w*b4.w;
    }
}

// ---------------- unified GEMM: As [k][row] x W[OO][CC] staged in k-slabs -> acc ----------------
template<int CC, int OO>
__device__ __forceinline__ void gemm_slab(const float* __restrict__ W, int t, int i, int j,
                                          float* As, float* Bs, float (&acc)[4][OO/64][4]){
    constexpr int KS = (4096/OO) < 32 ? (4096/OO) : 32;
    constexpr int QQ = KS/4;
    constexpr int NSLOT = KS*OO/4;
    for (int k0=0; k0<CC; k0+=KS){
        __syncthreads();
#pragma unroll
        for (int it=0; it<NSLOT/256; ++it){
            int slot = t + it*256;
            int o = slot / QQ, qq = slot % QQ;
            float4 wv = *(const float4*)(W + o*CC + k0 + qq*4);
            Bs[(qq*4+0)*OO + o] = wv.x; Bs[(qq*4+1)*OO + o] = wv.y;
            Bs[(qq*4+2)*OO + o] = wv.z; Bs[(qq*4+3)*OO + o] = wv.w;
        }
        __syncthreads();
#pragma unroll 4
        for (int kk=0; kk<KS; ++kk){
            float4 a4 = *(const float4*)&As[(k0+kk)*64 + i*4];
            fma_tile<OO/64>(acc, a4, &Bs[kk*OO], j*4);
        }
    }
    __syncthreads();
}

template<int UU>
__device__ __forceinline__ void bias_add(float (&acc)[4][UU][4], const float* __restrict__ bsrc, int j){
#pragma unroll
    for (int uu=0; uu<UU; ++uu)
#pragma unroll
    for (int e=0; e<4; ++e){
        float bb = bsrc[j*4 + 64*uu + e];
#pragma unroll
        for (int rr=0; rr<4; ++rr) acc[rr][uu][e] += bb;
    }
}

template<int UU>
__device__ __forceinline__ void act_to_As(float (&acc)[4][UU][4], const float* __restrict__ bsrc,
                                          const float* __restrict__ sc, const float* __restrict__ sh,
                                          int i, int j, float* As){
#pragma unroll
    for (int uu=0; uu<UU; ++uu)
#pragma unroll
    for (int e=0; e<4; ++e){
        int c = j*4 + 64*uu + e;
        float bb = bsrc[c], scv = sc[c], shv = sh[c];
#pragma unroll
        for (int rr=0; rr<4; ++rr)
            As[c*64 + i*4+rr] = fmaxf(0.f, (acc[rr][uu][e]+bb)*scv + shv);
    }
}

template<int UU>
__device__ __forceinline__ void zstore(float (&acc)[4][UU][4], u16* __restrict__ zbuf, int m0, int i, int j){
    constexpr int OO = UU*64;
#pragma unroll
    for (int rr=0; rr<4; ++rr){
        size_t row = (size_t)(m0 + i*4 + rr);
#pragma unroll
        for (int uu=0; uu<UU; ++uu){
            ushort4 o4;
            o4.x = f2bf(acc[rr][uu][0]); o4.y = f2bf(acc[rr][uu][1]);
            o4.z = f2bf(acc[rr][uu][2]); o4.w = f2bf(acc[rr][uu][3]);
            *(ushort4*)&zbuf[row*OO + j*4 + 64*uu] = o4;
        }
    }
}

template<int OO>
__device__ __forceinline__ void zload_to_As(const u16* __restrict__ zbuf, int m0,
                                            const float* __restrict__ sc, const float* __restrict__ sh,
                                            int t, float* As){
    constexpr int CQ = OO/4;
    constexpr int ITZ = 64*CQ/256;
#pragma unroll
    for (int it=0; it<ITZ; ++it){
        int slot = t + it*256;
        int r = slot / CQ, cq = slot % CQ;
        ushort4 zv = *(const ushort4*)&zbuf[((size_t)(m0+r))*OO + cq*4];
        int c = cq*4;
        As[(c+0)*64+r] = fmaxf(0.f, bf2f(zv.x)*sc[c+0] + sh[c+0]);
        As[(c+1)*64+r] = fmaxf(0.f, bf2f(zv.y)*sc[c+1] + sh[c+1]);
        As[(c+2)*64+r] = fmaxf(0.f, bf2f(zv.z)*sc[c+2] + sh[c+2]);
        As[(c+3)*64+r] = fmaxf(0.f, bf2f(zv.w)*sc[c+3] + sh[c+3]);
    }
}

// ---------------- stats / extrema epilogue ----------------
template<int UU, int K, bool EXT>
__device__ __forceinline__ void stats_write(float (&z)[4][UU][4], int t, int m0, int blk,
    float* scr, float* __restrict__ pS, float* __restrict__ pQ,
    float* __restrict__ gmax, float* __restrict__ gmin)
{
    constexpr int O = UU*64;
    int j = t & 15;
    float s1[UU][4], s2[UU][4], mx[UU][4], mn[UU][4];
#pragma unroll
    for (int uu=0; uu<UU; ++uu)
#pragma unroll
    for (int e=0; e<4; ++e){
        float v0=z[0][uu][e], v1=z[1][uu][e], v2=z[2][uu][e], v3=z[3][uu][e];
        s1[uu][e]=(v0+v1)+(v2+v3);
        s2[uu][e]=(v0*v0+v1*v1)+(v2*v2+v3*v3);
        if (EXT){
            mx[uu][e]=fmaxf(fmaxf(v0,v1),fmaxf(v2,v3));
            mn[uu][e]=fminf(fminf(v0,v1),fminf(v2,v3));
        }
    }
#pragma unroll
    for (int uu=0; uu<UU; ++uu)
#pragma unroll
    for (int e=0; e<4; ++e){
        s1[uu][e] += __shfl_xor(s1[uu][e],16); s1[uu][e] += __shfl_xor(s1[uu][e],32);
        s2[uu][e] += __shfl_xor(s2[uu][e],16); s2[uu][e] += __shfl_xor(s2[uu][e],32);
        if (EXT){
            mx[uu][e] = fmaxf(mx[uu][e], __shfl_xor(mx[uu][e],16)); mx[uu][e] = fmaxf(mx[uu][e], __shfl_xor(mx[uu][e],32));
            mn[uu][e] = fminf(mn[uu][e], __shfl_xor(mn[uu][e],16)); mn[uu][e] = fminf(mn[uu][e], __shfl_xor(mn[uu][e],32));
        }
    }
    int wv = t >> 6;
    if ((t & 63) < 16){
#pragma unroll
        for (int uu=0; uu<UU; ++uu)
#pragma unroll
        for (int e=0; e<4; ++e){
            int c = j*4 + 64*uu + e;
            scr[0*4*O + wv*O + c] = s1[uu][e];
            scr[1*4*O + wv*O + c] = s2[uu][e];
            if (EXT){
                scr[2*4*O + wv*O + c] = mx[uu][e];
                scr[3*4*O + wv*O + c] = mn[uu][e];
            }
        }
    }
    __syncthreads();
    for (int c=t; c<O; c+=256){
        float S = ((scr[c] + scr[O+c]) + (scr[2*O+c] + scr[3*O+c]));
        float Q = ((scr[4*O+c] + scr[5*O+c]) + (scr[6*O+c] + scr[7*O+c]));
        pS[(size_t)blk*O + c] = S;
        pQ[(size_t)blk*O + c] = Q;
        if (EXT){
            constexpr int G  = 64/K;
            constexpr int WG = K/16;
#pragma unroll
            for (int g=0; g<G; ++g){
                float M1 = scr[2*4*O + (g*WG)*O + c];
                float M2 = scr[3*4*O + (g*WG)*O + c];
#pragma unroll
                for (int ww=1; ww<WG; ++ww){
                    M1 = fmaxf(M1, scr[2*4*O + (g*WG+ww)*O + c]);
                    M2 = fminf(M2, scr[3*4*O + (g*WG+ww)*O + c]);
                }
                int bs = m0/K + g;
                gmax[(size_t)bs*O + c] = M1;
                gmin[(size_t)bs*O + c] = M2;
            }
        }
    }
}

template<int K>
__device__ __forceinline__ void gather_A0(const float* __restrict__ ptsT, const float* __restrict__ q,
                                          const int* __restrict__ gidx, int m0, int t, float* As){
    int r = t >> 2, q4 = t & 3;
    int m = m0 + r;
    int idx = gidx[m];
    int bs = m / K;
    int b = bs >> 10;
    const float* base = ptsT + ((size_t)b*NN + idx)*64;
    float qx=0.f, qy=0.f, qz=0.f;
    if (q4 == 0){ qx = q[bs*3]; qy = q[bs*3+1]; qz = q[bs*3+2]; }
#pragma unroll
    for (int ii=0; ii<4; ++ii){
        int c0 = q4*16 + ii*4;
        float4 v = *(const float4*)(base + c0);
        if (q4==0 && ii==0){ v.x -= qx; v.y -= qy; v.z -= qz; }
        As[(c0+0)*64 + r] = v.x; As[(c0+1)*64 + r] = v.y;
        As[(c0+2)*64 + r] = v.z; As[(c0+3)*64 + r] = v.w;
    }
}

// ---------------- fused MLP phases ----------------
template<int PHASE, int K, int O1, int O2, int O3>
__global__ __launch_bounds__(256) void fused_mlp(
    const float* __restrict__ ptsT, const float* __restrict__ q, const int* __restrict__ gidx,
    const float* __restrict__ W1, const float* __restrict__ b1,
    const float* __restrict__ W2, const float* __restrict__ b2,
    const float* __restrict__ W3, const float* __restrict__ b3,
    const float* __restrict__ sc1, const float* __restrict__ sh1,
    const float* __restrict__ sc2, const float* __restrict__ sh2,
    float* __restrict__ pS, float* __restrict__ pQ,
    float* __restrict__ gmax, float* __restrict__ gmin,
    u16* __restrict__ zbuf)
{
    __shared__ float As[8192];   // 32 KB
    __shared__ float Bs[4096];   // 16 KB
    int t = threadIdx.x;
    int m0 = blockIdx.x * 64;
    int j = t & 15, i = t >> 4;

    if constexpr (PHASE == 1){
        gather_A0<K>(ptsT, q, gidx, m0, t, As);
        float acc1[4][O1/64][4] = {};
        gemm_slab<64,O1>(W1, t, i, j, As, Bs, acc1);
        bias_add<O1/64>(acc1, b1, j);
        if (zbuf) zstore<O1/64>(acc1, zbuf, m0, i, j);
        stats_write<O1/64,K,false>(acc1, t, m0, blockIdx.x, Bs, pS, pQ, gmax, gmin);
        return;
    }

    if constexpr (PHASE == 2){
        if (zbuf){
            zload_to_As<O1>(zbuf, m0, sc1, sh1, t, As);
        } else {
            gather_A0<K>(ptsT, q, gidx, m0, t, As);
            float acc1[4][O1/64][4] = {};
            gemm_slab<64,O1>(W1, t, i, j, As, Bs, acc1);
            act_to_As<O1/64>(acc1, b1, sc1, sh1, i, j, As);
        }
        float acc2[4][O2/64][4] = {};
        gemm_slab<O1,O2>(W2, t, i, j, As, Bs, acc2);
        bias_add<O2/64>(acc2, b2, j);
        if (zbuf) zstore<O2/64>(acc2, zbuf, m0, i, j);   // overwrites z1 rows (block-local, safe)
        stats_write<O2/64,K,false>(acc2, t, m0, blockIdx.x, Bs, pS, pQ, gmax, gmin);
        return;
    }

    if constexpr (PHASE == 3){
        gather_A0<K>(ptsT, q, gidx, m0, t, As);
        float acc1[4][O1/64][4] = {};
        gemm_slab<64,O1>(W1, t, i, j, As, Bs, acc1);
        act_to_As<O1/64>(acc1, b1, sc1, sh1, i, j, As);
        float acc2[4][O2/64][4] = {};
        gemm_slab<O1,O2>(W2, t, i, j, As, Bs, acc2);
        act_to_As<O2/64>(acc2, b2, sc2, sh2, i, j, As);
    } else {
        // PHASE 4
        zload_to_As<O2>(zbuf, m0, sc2, sh2, t, As);
    }

    float acc3[4][O3/64][4] = {};
    gemm_slab<O2,O3>(W3, t, i, j, As, Bs, acc3);
    bias_add<O3/64>(acc3, b3, j);
    stats_write<O3/64,K,true>(acc3, t, m0, blockIdx.x, Bs, pS, pQ, gmax, gmin);
}

// ---------------- finalize BN stats (fp64 accumulation) ----------------
__global__ __launch_bounds__(256) void finalize_d_kernel(const float* __restrict__ pS, const float* __restrict__ pQ,
                                      const float* __restrict__ g, const float* __restrict__ bt,
                                      float* __restrict__ sc, float* __restrict__ sh, int nb, double invM){
    __shared__ double red[512];
    int c = blockIdx.x;
    int O = gridDim.x;
    int t = threadIdx.x;
    double S=0.0, Q=0.0;
    for (int v=t; v<nb; v+=256){ S += (double)pS[(size_t)v*O + c]; Q += (double)pQ[(size_t)v*O + c]; }
    red[t]=S; red[256+t]=Q;
    __syncthreads();
    for (int s=128; s>0; s>>=1){
        if (t<s){ red[t]+=red[t+s]; red[256+t]+=red[256+t+s]; }
        __syncthreads();
    }
    if (t==0){
        double mean = red[0]*invM;
        double var  = red[256]*invM - mean*mean;
        double scale = (double)g[c] / sqrt(var + 1e-5);
        sc[c] = (float)scale;
        sh[c] = (float)((double)bt[c] - mean*scale);
    }
}

// ---------------- BN+relu on pooled extrema -> output (fp32) ----------------
__global__ void final_out_kernel(const float* __restrict__ gmax, const float* __restrict__ gmin,
                                 const float* __restrict__ sc, const float* __restrict__ sh,
                                 float* __restrict__ outp, int O, int logO, int chbase){
    int gid = blockIdx.x*256 + threadIdx.x;
    int c  = gid & (O-1);
    int bs = gid >> logO;
    int b = bs >> 10, s = bs & 1023;
    float scale = sc[c];
    float v = (scale >= 0.f) ? gmax[gid] : gmin[gid];
    float r = fmaxf(0.f, scale*v + sh[c]);
    outp[((size_t)(b*640 + chbase + c))*SS + s] = r;
}

__global__ void ws_marker_kernel(float* outp, float wsval){ if (threadIdx.x==0) outp[0] = wsval; }

template<int K, int O1, int O2, int O3>
static void run_branch(const float* ptsT, const float* q, const int* gidx,
                       float* pS, float* pQ, float* gmax, float* gmin,
                       float* sc1, float* sh1, float* sc2, float* sh2, float* sc3, float* sh3,
                       u16* z2buf, bool use_z,
                       void* const* d_in, int wbase, float* np_out, int chbase, hipStream_t stream)
{
    const int M = BB*SS*K;
    const int nb = M/64;
    auto wp = [&](int jl, int which)->const float* { return (const float*)d_in[2 + (wbase+jl)*4 + which]; };
    const double invM = 1.0 / (double)M;
    u16* zb = use_z ? z2buf : (u16*)nullptr;

    fused_mlp<1,K,O1,O2,O3><<<nb,256,0,stream>>>(ptsT,q,gidx,
        wp(0,0),wp(0,1), wp(1,0),wp(1,1), wp(2,0),wp(2,1),
        sc1,sh1, sc2,sh2, pS,pQ, gmax,gmin, zb);
    finalize_d_kernel<<<O1,256,0,stream>>>(pS,pQ, wp(0,2), wp(0,3), sc1, sh1, nb, invM);

    fused_mlp<2,K,O1,O2,O3><<<nb,256,0,stream>>>(ptsT,q,gidx,
        wp(0,0),wp(0,1), wp(1,0),wp(1,1), wp(2,0),wp(2,1),
        sc1,sh1, sc2,sh2, pS,pQ, gmax,gmin, zb);
    finalize_d_kernel<<<O2,256,0,stream>>>(pS,pQ, wp(1,2), wp(1,3), sc2, sh2, nb, invM);

    if (use_z){
        fused_mlp<4,K,O1,O2,O3><<<nb,256,0,stream>>>(ptsT,q,gidx,
            wp(0,0),wp(0,1), wp(1,0),wp(1,1), wp(2,0),wp(2,1),
            sc1,sh1, sc2,sh2, pS,pQ, gmax,gmin, z2buf);
    } else {
        fused_mlp<3,K,O1,O2,O3><<<nb,256,0,stream>>>(ptsT,q,gidx,
            wp(0,0),wp(0,1), wp(1,0),wp(1,1), wp(2,0),wp(2,1),
            sc1,sh1, sc2,sh2, pS,pQ, gmax,gmin, nullptr);
    }
    finalize_d_kernel<<<O3,256,0,stream>>>(pS,pQ, wp(2,2), wp(2,3), sc3, sh3, nb, invM);

    final_out_kernel<<<(BB*SS*O3)/256,256,0,stream>>>(gmax,gmin, sc3,sh3, np_out, O3, (O3==256?8:7), chbase);
}

extern "C" void kernel_launch(void* const* d_in, const int* in_sizes, int n_in,
                              void* d_out, int out_size, void* d_ws, size_t ws_size,
                              hipStream_t stream)
{
    const float* xyz = (const float*)d_in[0];
    const float* pts = (const float*)d_in[1];
    float* outp = (float*)d_out;

    char* wsb = (char*)d_ws;
    size_t off = 0;
    auto alloc = [&](size_t bytes) -> void* {
        off = (off + 255) & ~(size_t)255;
        void* p = wsb + off;
        off += bytes;
        return p;
    };
    int*   fps_idx = (int*)  alloc((size_t)BB*SS*4);
    float* q       = (float*)alloc((size_t)BB*SS*3*4);
    int*   idx0    = (int*)  alloc((size_t)BB*SS*16*4);
    int*   idx1    = (int*)  alloc((size_t)BB*SS*32*4);
    int*   idx2    = (int*)  alloc((size_t)BB*SS*64*4);
    float* ptsT    = (float*)alloc((size_t)BB*NN*64*4);
    float* pS      = (float*)alloc((size_t)8192*256*4);
    float* pQ      = (float*)alloc((size_t)8192*256*4);
    float* gmax    = (float*)alloc((size_t)8192*256*4);
    float* gmin    = (float*)alloc((size_t)8192*256*4);
    float* sc1     = (float*)alloc(256*4);
    float* sh1     = (float*)alloc(256*4);
    float* sc2     = (float*)alloc(256*4);
    float* sh2     = (float*)alloc(256*4);
    float* sc3     = (float*)alloc(256*4);
    float* sh3     = (float*)alloc(256*4);

    if (off > ws_size){
        ws_marker_kernel<<<1,64,0,stream>>>(outp, (float)ws_size);
        return;
    }

    u16* z2buf = (u16*)alloc((size_t)BB*SS*64*128*2);
    bool use_z = (off <= ws_size);

    build_ptsT_kernel<<<dim3(NN/64, BB), 256, 0, stream>>>(xyz, pts, ptsT);
    fps_kernel<<<BB, 512, 0, stream>>>(xyz, fps_idx);
    gather_q_kernel<<<32, 256, 0, stream>>>(xyz, fps_idx, q, outp);

    const float r2a = (float)(0.1*0.1);
    const float r2b = (float)(0.2*0.2);
    const float r2c = (float)(0.4*0.4);
    ballquery_kernel<<<2048, 256, 0, stream>>>(xyz, q, idx0, idx1, idx2, r2a, r2b, r2c);

    float* np_out = outp + (size_t)BB*3*SS;
    run_branch<16, 64, 64,128>(ptsT, q, idx0, pS,pQ, gmax,gmin, sc1,sh1,sc2,sh2,sc3,sh3, z2buf, use_z, d_in, 0, np_out,   0, stream);
    run_branch<32,128,128,256>(ptsT, q, idx1, pS,pQ, gmax,gmin, sc1,sh1,sc2,sh2,sc3,sh3, z2buf, use_z, d_in, 3, np_out, 128, stream);
    run_branch<64,128,128,256>(ptsT, q, idx2, pS,pQ, gmax,gmin, sc1,sh1,sc2,sh2,sc3,sh3, z2buf, use_z, d_in, 6, np_out, 384, stream);

    hipError_t e = hipGetLastError();
    if (e != hipSuccess){
        ws_marker_kernel<<<1,64,0,stream>>>(outp, 1000.0f + (float)(int)e);
    }
}